// Round 5
// baseline (384.019 us; speedup 1.0000x reference)
//
#include <hip/hip_runtime.h>

#define N_TOK 343
#define NP 352        // padded tokens (22*16)
#define C_DIM 96
#define HEADS 3
#define HD 32
#define B_SZ 256
#define NW 32
#define QKV_COLS 288

#define QKV_ELEMS (B_SZ * HEADS * N_TOK * HD)  // 8429568
#define X2_ELEMS ((long)B_SZ * N_TOK * C_DIM)  // 8429568
#define CMB_ELEMS ((long)NW * HEADS * N_TOK * NP)

typedef _Float16 f16;
typedef _Float16 f16x2 __attribute__((ext_vector_type(2)));
typedef _Float16 f16x4 __attribute__((ext_vector_type(4)));
typedef _Float16 f16x8 __attribute__((ext_vector_type(8)));
typedef float f32x4 __attribute__((ext_vector_type(4)));

// ---------------------------------------------------------------------------
// Kernel W: transpose+cast weights to f16. wt_qkv[col][k], wt_proj[col][k].
// ---------------------------------------------------------------------------
__global__ __launch_bounds__(256) void wprep_kernel(
    const float* __restrict__ w_qkv, const float* __restrict__ w_proj,
    f16* __restrict__ wt_qkv, f16* __restrict__ wt_proj) {
  const int e = blockIdx.x * 256 + threadIdx.x;
  if (e < QKV_COLS * 96) {
    const int cc = e / 96, k = e % 96;
    wt_qkv[e] = (f16)w_qkv[k * QKV_COLS + cc];
  } else {
    const int e2 = e - QKV_COLS * 96;
    if (e2 < 96 * 96) {
      const int cc = e2 / 96, k = e2 % 96;
      wt_proj[e2] = (f16)w_proj[k * 96 + cc];
    }
  }
}

// ---------------------------------------------------------------------------
// Kernel P: fused bias+mask -> CMB[w][h][343][352] f16. Pad keys get -1000.
// ---------------------------------------------------------------------------
__global__ __launch_bounds__(256) void cmb_kernel(
    const float* __restrict__ mask, const float* __restrict__ bias_table,
    f16* __restrict__ cmb) {
  const long e = (long)blockIdx.x * 256 + threadIdx.x;
  if (e >= CMB_ELEMS) return;
  const int key = (int)(e % NP);
  const long rowid = e / NP;
  const int q = (int)(rowid % N_TOK);
  const int wh = (int)(rowid / N_TOK);
  const int h = wh % HEADS;
  const int w = wh / HEADS;
  float val;
  if (key < N_TOK) {
    const int bn = (q / 49) * 169 + ((q / 7) % 7) * 13 + (q % 7);
    const int bm = (key / 49) * 169 + ((key / 7) % 7) * 13 + (key % 7);
    val = bias_table[(bn - bm + 1098) * HEADS + h] +
          mask[((long)w * N_TOK + q) * N_TOK + key];
  } else {
    val = -1000.f;
  }
  cmb[e] = (f16)val;
}

// ---------------------------------------------------------------------------
// Kernel A: MFMA qkv. Block = 64 rows (4 waves x 16), 288 cols.
// Q/K epilogue: per (which,h) pair stage 16x32 tile in LDS, emit coalesced
// f16x8 stores. V: scalar stores (layout [b][h][n][32], as before).
// ---------------------------------------------------------------------------
__global__ __launch_bounds__(256) void qkv_mfma_kernel(
    const float* __restrict__ x, const f16* __restrict__ wt,
    const float* __restrict__ bias,
    f16* __restrict__ Q, f16* __restrict__ K, f16* __restrict__ V) {
  __shared__ f16 sh[4][16][40];  // per-wave transpose tile (80B rows, 16B-mult)
  const int tid = threadIdx.x;
  const int wave = tid >> 6, lane = tid & 63;
  const int c = lane & 15, g = lane >> 4;
  const long rowTile = (long)blockIdx.x * 64 + wave * 16;
  const long arow = rowTile + c;

  // A-frags: x rows cast f32 -> f16
  f16x8 af[3];
#pragma unroll
  for (int ks = 0; ks < 3; ++ks) {
    const float* px = x + arow * 96 + ks * 32 + g * 8;
    const float4 lo = *(const float4*)px;
    const float4 hi = *(const float4*)(px + 4);
    f16x8 v;
    v[0] = (f16)lo.x; v[1] = (f16)lo.y; v[2] = (f16)lo.z; v[3] = (f16)lo.w;
    v[4] = (f16)hi.x; v[5] = (f16)hi.y; v[6] = (f16)hi.z; v[7] = (f16)hi.w;
    af[ks] = v;
  }

  // per-lane ids for the coalesced Q/K store (row = rowTile + lane/4)
  const int rowL = (int)rowTile + (lane >> 2);
  const int bL = rowL / N_TOK, nL = rowL % N_TOK;
  // per-r ids for V scalar stores (rows 4g+r)
  int bidx[4], nidx[4];
#pragma unroll
  for (int r = 0; r < 4; ++r) {
    const int row = (int)rowTile + 4 * g + r;
    bidx[r] = row / N_TOK;
    nidx[r] = row % N_TOK;
  }

  const f32x4 zero = {0.f, 0.f, 0.f, 0.f};
  const float scale = 0.17677669529663687f;  // hd^-0.5

#pragma unroll
  for (int p = 0; p < 9; ++p) {              // pair p: cts 2p, 2p+1
    const int which = p / 3;                 // 0=q 1=k 2=v
    const int h = p % 3;
    const float mult = (which == 0) ? scale : 1.0f;
#pragma unroll
    for (int e = 0; e < 2; ++e) {
      const int ct = 2 * p + e;
      f32x4 acc = zero;
#pragma unroll
      for (int ks = 0; ks < 3; ++ks) {
        const f16x8 bf = *(const f16x8*)(wt + (ct * 16 + c) * 96 + ks * 32 + g * 8);
        acc = __builtin_amdgcn_mfma_f32_16x16x32_f16(af[ks], bf, acc, 0, 0, 0);
      }
      const float bv = bias[ct * 16 + c];
      if (which < 2) {
        // stage into LDS transpose tile: row 4g+r, d = e*16+c
#pragma unroll
        for (int r = 0; r < 4; ++r)
          sh[wave][4 * g + r][(e << 4) + c] = (f16)((acc[r] + bv) * mult);
      } else {
        const int d = ((ct & 1) << 4) + c;
#pragma unroll
        for (int r = 0; r < 4; ++r) {
          V[(((long)bidx[r] * HEADS + h) * N_TOK + nidx[r]) * HD + d] =
              (f16)(acc[r] + bv);
        }
      }
    }
    if (which < 2) {
      __builtin_amdgcn_wave_barrier();
      const f16x8 po = *(const f16x8*)&sh[wave][lane >> 2][(lane & 3) * 8];
      __builtin_amdgcn_wave_barrier();
      f16* dst = (which == 0) ? Q : K;
      *(f16x8*)(dst + (((long)bL * HEADS + h) * N_TOK + nL) * HD + (lane & 3) * 8) = po;
    }
  }
}

// ---------------------------------------------------------------------------
// Kernel B: MFMA attention v2. LDS = Vt only (22.8KB -> 4 blocks/CU).
// K frags read from global (L1/L2-resident). P stays in-lane via k-slot
// permutation: slot j of PV-mfma <-> keys {4g+j | 16+4g+(j-4)}; V frags read
// with matching offsets (2x ds_read_b64 per frag).
// ---------------------------------------------------------------------------
__global__ __launch_bounds__(512, 6) void attn_kernel(
    const f16* __restrict__ Qh, const f16* __restrict__ Kh,
    const f16* __restrict__ Vh, const f16* __restrict__ CMB,
    f16* __restrict__ X2h) {
  __shared__ f16 Vt[HD][356];  // stride 178 words: 16 distinct banks, 8B-aligned

  const int blk = blockIdx.x;
  const int b = blk / HEADS;
  const int h = blk % HEADS;
  const int tid = threadIdx.x;
  const int wave = tid >> 6;
  const int lane = tid & 63;
  const int c = lane & 15;
  const int g = lane >> 4;

  const f16* Kg = Kh + (long)blk * (N_TOK * HD);
  const f16* Vg = Vh + (long)blk * (N_TOK * HD);
  const f16* Qg = Qh + (long)blk * (N_TOK * HD);

  // stage V transposed; zero-fill tail cols (avoid stale-LDS NaN * P=0)
  for (int i = tid; i < N_TOK * 16; i += 512) {
    const int n = i >> 4, dp = i & 15;
    const f16x2 v2 = *(const f16x2*)(Vg + n * HD + dp * 2);
    Vt[2 * dp][n] = v2.x;
    Vt[2 * dp + 1][n] = v2.y;
  }
  for (int i = tid; i < HD * 13; i += 512) Vt[i / 13][N_TOK + i % 13] = (f16)0;
  __syncthreads();

  const int w = b & (NW - 1);
  const f32x4 zero = {0.f, 0.f, 0.f, 0.f};

  for (int qt = wave; qt < NP / 16; qt += 8) {
    const int q = qt * 16 + c;
    const int qrow = (q < N_TOK) ? q : (N_TOK - 1);
    const f16x8 qf = *(const f16x8*)(Qg + qrow * HD + g * 8);
    const f16* cmrow = CMB + ((long)(w * HEADS + h) * N_TOK + qrow) * NP;

    f32x4 acc0 = zero, acc1 = zero;
    float lsum = 0.f;

    for (int kt = 0; kt < NP / 32; ++kt) {
      const f16x8 kf0 = *(const f16x8*)(Kg + (32 * kt + c) * HD + g * 8);
      const f16x8 kf1 = *(const f16x8*)(Kg + (32 * kt + 16 + c) * HD + g * 8);
      const f16x4 cm0 = *(const f16x4*)(cmrow + 32 * kt + 4 * g);
      const f16x4 cm1 = *(const f16x4*)(cmrow + 32 * kt + 16 + 4 * g);

      const f32x4 s0 = __builtin_amdgcn_mfma_f32_16x16x32_f16(kf0, qf, zero, 0, 0, 0);
      const f32x4 s1 = __builtin_amdgcn_mfma_f32_16x16x32_f16(kf1, qf, zero, 0, 0, 0);

      float p0[4], p1[4];
#pragma unroll
      for (int r = 0; r < 4; ++r) {
        p0[r] = __expf(s0[r] + (float)cm0[r]);
        p1[r] = __expf(s1[r] + (float)cm1[r]);
        lsum += p0[r] + p1[r];
      }
      // in-lane P fragment: slots 0-3 = keys 4g+r, slots 4-7 = keys 16+4g+r
      const f16x2 a0 = __builtin_bit_cast(f16x2, __builtin_amdgcn_cvt_pkrtz(p0[0], p0[1]));
      const f16x2 a1 = __builtin_bit_cast(f16x2, __builtin_amdgcn_cvt_pkrtz(p0[2], p0[3]));
      const f16x2 a2 = __builtin_bit_cast(f16x2, __builtin_amdgcn_cvt_pkrtz(p1[0], p1[1]));
      const f16x2 a3 = __builtin_bit_cast(f16x2, __builtin_amdgcn_cvt_pkrtz(p1[2], p1[3]));
      const f16x4 plo = __builtin_shufflevector(a0, a1, 0, 1, 2, 3);
      const f16x4 phi = __builtin_shufflevector(a2, a3, 0, 1, 2, 3);
      const f16x8 pf = __builtin_shufflevector(plo, phi, 0, 1, 2, 3, 4, 5, 6, 7);

      // V frags with matching key-slot offsets
      const f16x4 va0 = *(const f16x4*)&Vt[c][32 * kt + 4 * g];
      const f16x4 va1 = *(const f16x4*)&Vt[c][32 * kt + 16 + 4 * g];
      const f16x4 vb0 = *(const f16x4*)&Vt[16 + c][32 * kt + 4 * g];
      const f16x4 vb1 = *(const f16x4*)&Vt[16 + c][32 * kt + 16 + 4 * g];
      const f16x8 vf0 = __builtin_shufflevector(va0, va1, 0, 1, 2, 3, 4, 5, 6, 7);
      const f16x8 vf1 = __builtin_shufflevector(vb0, vb1, 0, 1, 2, 3, 4, 5, 6, 7);

      acc0 = __builtin_amdgcn_mfma_f32_16x16x32_f16(vf0, pf, acc0, 0, 0, 0);
      acc1 = __builtin_amdgcn_mfma_f32_16x16x32_f16(vf1, pf, acc1, 0, 0, 0);
    }

    lsum += __shfl_xor(lsum, 16);
    lsum += __shfl_xor(lsum, 32);
    const float inv = 1.f / lsum;

    if (q < N_TOK) {
      f16* orow = X2h + ((long)b * N_TOK + q) * C_DIM + h * HD;
      f16x4 o0, o1;
#pragma unroll
      for (int r = 0; r < 4; ++r) {
        o0[r] = (f16)(acc0[r] * inv);
        o1[r] = (f16)(acc1[r] * inv);
      }
      *(f16x4*)(orow + 4 * g) = o0;
      *(f16x4*)(orow + 16 + 4 * g) = o1;
    }
  }
}

// ---------------------------------------------------------------------------
// Kernel C: MFMA proj. out = X2h @ wt_proj + b_proj (f32), LDS-bounced
// coalesced f32x4 stores.
// ---------------------------------------------------------------------------
__global__ __launch_bounds__(256) void proj_mfma_kernel(
    const f16* __restrict__ X2h, const f16* __restrict__ wt,
    const float* __restrict__ bias, float* __restrict__ out) {
  __shared__ float shp[4][16][100];  // 400B rows (16B-mult), word-stride 100
  const int tid = threadIdx.x;
  const int wave = tid >> 6, lane = tid & 63;
  const int c = lane & 15, g = lane >> 4;
  const long rowTile = (long)blockIdx.x * 64 + wave * 16;
  const long arow = rowTile + c;

  f16x8 af[3];
#pragma unroll
  for (int ks = 0; ks < 3; ++ks)
    af[ks] = *(const f16x8*)(X2h + arow * 96 + ks * 32 + g * 8);

  const f32x4 zero = {0.f, 0.f, 0.f, 0.f};
#pragma unroll
  for (int ct = 0; ct < 6; ++ct) {
    f32x4 acc = zero;
#pragma unroll
    for (int ks = 0; ks < 3; ++ks) {
      const f16x8 bf = *(const f16x8*)(wt + (ct * 16 + c) * 96 + ks * 32 + g * 8);
      acc = __builtin_amdgcn_mfma_f32_16x16x32_f16(af[ks], bf, acc, 0, 0, 0);
    }
    const float bv = bias[ct * 16 + c];
#pragma unroll
    for (int r = 0; r < 4; ++r)
      shp[wave][4 * g + r][ct * 16 + c] = acc[r] + bv;
  }
  __builtin_amdgcn_wave_barrier();
  // coalesced writeback: 16 rows x 24 f32x4 chunks = 384 tasks, 6 rounds
#pragma unroll
  for (int i = 0; i < 6; ++i) {
    const int u = lane + 64 * i;
    const int row = u / 24, ch = u % 24;
    const float4 v = *(const float4*)&shp[wave][row][ch * 4];
    *(float4*)(out + (rowTile + row) * 96 + ch * 4) = v;
  }
}

// ---------------------------------------------------------------------------
extern "C" void kernel_launch(void* const* d_in, const int* in_sizes, int n_in,
                              void* d_out, int out_size, void* d_ws, size_t ws_size,
                              hipStream_t stream) {
  const float* x          = (const float*)d_in[0];
  const float* mask       = (const float*)d_in[1];
  const float* w_qkv      = (const float*)d_in[2];
  const float* b_qkv      = (const float*)d_in[3];
  const float* bias_table = (const float*)d_in[4];
  const float* w_proj     = (const float*)d_in[5];
  const float* b_proj     = (const float*)d_in[6];
  float* out = (float*)d_out;

  f16* Qh = (f16*)d_ws;
  f16* Kh = Qh + QKV_ELEMS;
  f16* Vh = Kh + QKV_ELEMS;
  f16* X2h = Vh + QKV_ELEMS;
  f16* CMB = X2h + X2_ELEMS;
  f16* WTQ = CMB + CMB_ELEMS;
  f16* WTP = WTQ + QKV_COLS * 96;

  const int cmbBlocks = (int)((CMB_ELEMS + 255) / 256);
  const int wBlocks = (QKV_COLS * 96 + 96 * 96 + 255) / 256;  // 144
  const int gemmBlocks = (B_SZ * N_TOK) / 64;                  // 1372

  wprep_kernel<<<wBlocks, 256, 0, stream>>>(w_qkv, w_proj, WTQ, WTP);
  cmb_kernel<<<cmbBlocks, 256, 0, stream>>>(mask, bias_table, CMB);
  qkv_mfma_kernel<<<gemmBlocks, 256, 0, stream>>>(x, WTQ, b_qkv, Qh, Kh, Vh);
  attn_kernel<<<B_SZ * HEADS, 512, 0, stream>>>(Qh, Kh, Vh, CMB, X2h);
  proj_mfma_kernel<<<gemmBlocks, 256, 0, stream>>>(X2h, WTP, b_proj, out);
}

// Round 6
// 378.358 us; speedup vs baseline: 1.0150x; 1.0150x over previous
//
#include <hip/hip_runtime.h>

#define N_TOK 343
#define NP 352        // padded tokens (22*16)
#define C_DIM 96
#define HEADS 3
#define HD 32
#define B_SZ 256
#define NW 32
#define QKV_COLS 288

#define QKV_ELEMS (B_SZ * HEADS * N_TOK * HD)  // 8429568
#define X2_ELEMS ((long)B_SZ * N_TOK * C_DIM)  // 8429568
#define CMB_ELEMS ((long)NW * HEADS * N_TOK * NP)

typedef _Float16 f16;
typedef _Float16 f16x2 __attribute__((ext_vector_type(2)));
typedef _Float16 f16x4 __attribute__((ext_vector_type(4)));
typedef _Float16 f16x8 __attribute__((ext_vector_type(8)));
typedef float f32x4 __attribute__((ext_vector_type(4)));

// ---------------------------------------------------------------------------
// Kernel W: transpose+cast weights to f16. wt_qkv[col][k], wt_proj[col][k].
// ---------------------------------------------------------------------------
__global__ __launch_bounds__(256) void wprep_kernel(
    const float* __restrict__ w_qkv, const float* __restrict__ w_proj,
    f16* __restrict__ wt_qkv, f16* __restrict__ wt_proj) {
  const int e = blockIdx.x * 256 + threadIdx.x;
  if (e < QKV_COLS * 96) {
    const int cc = e / 96, k = e % 96;
    wt_qkv[e] = (f16)w_qkv[k * QKV_COLS + cc];
  } else {
    const int e2 = e - QKV_COLS * 96;
    if (e2 < 96 * 96) {
      const int cc = e2 / 96, k = e2 % 96;
      wt_proj[e2] = (f16)w_proj[k * 96 + cc];
    }
  }
}

// ---------------------------------------------------------------------------
// Kernel P: fused bias+mask -> CMB[w][h][343][352] f16. Pad keys get -1000.
// ---------------------------------------------------------------------------
__global__ __launch_bounds__(256) void cmb_kernel(
    const float* __restrict__ mask, const float* __restrict__ bias_table,
    f16* __restrict__ cmb) {
  const long e = (long)blockIdx.x * 256 + threadIdx.x;
  if (e >= CMB_ELEMS) return;
  const int key = (int)(e % NP);
  const long rowid = e / NP;
  const int q = (int)(rowid % N_TOK);
  const int wh = (int)(rowid / N_TOK);
  const int h = wh % HEADS;
  const int w = wh / HEADS;
  float val;
  if (key < N_TOK) {
    const int bn = (q / 49) * 169 + ((q / 7) % 7) * 13 + (q % 7);
    const int bm = (key / 49) * 169 + ((key / 7) % 7) * 13 + (key % 7);
    val = bias_table[(bn - bm + 1098) * HEADS + h] +
          mask[((long)w * N_TOK + q) * N_TOK + key];
  } else {
    val = -1000.f;
  }
  cmb[e] = (f16)val;
}

// ---------------------------------------------------------------------------
// Kernel A: MFMA qkv. Block = 64 rows (4 waves x 16), 288 cols.
// All epilogues LDS-bounced to coalesced f16x8 stores (Q,K,V same layout).
// ---------------------------------------------------------------------------
__global__ __launch_bounds__(256) void qkv_mfma_kernel(
    const float* __restrict__ x, const f16* __restrict__ wt,
    const float* __restrict__ bias,
    f16* __restrict__ Q, f16* __restrict__ K, f16* __restrict__ V) {
  __shared__ f16 sh[4][16][40];  // per-wave transpose tile
  const int tid = threadIdx.x;
  const int wave = tid >> 6, lane = tid & 63;
  const int c = lane & 15, g = lane >> 4;
  const long rowTile = (long)blockIdx.x * 64 + wave * 16;
  const long arow = rowTile + c;

  // A-frags: x rows cast f32 -> f16
  f16x8 af[3];
#pragma unroll
  for (int ks = 0; ks < 3; ++ks) {
    const float* px = x + arow * 96 + ks * 32 + g * 8;
    const float4 lo = *(const float4*)px;
    const float4 hi = *(const float4*)(px + 4);
    f16x8 v;
    v[0] = (f16)lo.x; v[1] = (f16)lo.y; v[2] = (f16)lo.z; v[3] = (f16)lo.w;
    v[4] = (f16)hi.x; v[5] = (f16)hi.y; v[6] = (f16)hi.z; v[7] = (f16)hi.w;
    af[ks] = v;
  }

  // per-lane ids for the coalesced store (row = rowTile + lane/4)
  const int rowL = (int)rowTile + (lane >> 2);
  const int bL = rowL / N_TOK, nL = rowL % N_TOK;

  const f32x4 zero = {0.f, 0.f, 0.f, 0.f};
  const float scale = 0.17677669529663687f;  // hd^-0.5

#pragma unroll
  for (int p = 0; p < 9; ++p) {              // pair p: cts 2p, 2p+1
    const int which = p / 3;                 // 0=q 1=k 2=v
    const int h = p % 3;
    const float mult = (which == 0) ? scale : 1.0f;
#pragma unroll
    for (int e = 0; e < 2; ++e) {
      const int ct = 2 * p + e;
      f32x4 acc = zero;
#pragma unroll
      for (int ks = 0; ks < 3; ++ks) {
        const f16x8 bf = *(const f16x8*)(wt + (ct * 16 + c) * 96 + ks * 32 + g * 8);
        acc = __builtin_amdgcn_mfma_f32_16x16x32_f16(af[ks], bf, acc, 0, 0, 0);
      }
      const float bv = bias[ct * 16 + c];
#pragma unroll
      for (int r = 0; r < 4; ++r)
        sh[wave][4 * g + r][(e << 4) + c] = (f16)((acc[r] + bv) * mult);
    }
    __builtin_amdgcn_wave_barrier();
    const f16x8 po = *(const f16x8*)&sh[wave][lane >> 2][(lane & 3) * 8];
    __builtin_amdgcn_wave_barrier();
    f16* dst = (which == 0) ? Q : (which == 1) ? K : V;
    *(f16x8*)(dst + (((long)bL * HEADS + h) * N_TOK + nL) * HD + (lane & 3) * 8) = po;
  }
}

// ---------------------------------------------------------------------------
// Kernel B: MFMA attention v3. K+V staged in LDS (51KB -> 3 blocks/CU).
// In-lane P via k-slot permutation: slot j <-> keys {4g+j | 16+4g+(j-4)};
// V frags read at matching offsets (2x ds_read_b64 per frag). No P buffer,
// no per-K-step barriers.
// ---------------------------------------------------------------------------
__global__ __launch_bounds__(512, 6) void attn_kernel(
    const f16* __restrict__ Qh, const f16* __restrict__ Kh,
    const f16* __restrict__ Vh, const f16* __restrict__ CMB,
    f16* __restrict__ X2h) {
  __shared__ f16 Ks[NP][40];   // 80B stride: 2-way bank aliasing (free)
  __shared__ f16 Vt[HD][356];  // 712B stride: even-bank spread

  const int blk = blockIdx.x;
  const int b = blk / HEADS;
  const int h = blk % HEADS;
  const int tid = threadIdx.x;
  const int wave = tid >> 6;
  const int lane = tid & 63;
  const int c = lane & 15;
  const int g = lane >> 4;

  const f16* Kg = Kh + (long)blk * (N_TOK * HD);
  const f16* Vg = Vh + (long)blk * (N_TOK * HD);
  const f16* Qg = Qh + (long)blk * (N_TOK * HD);

  // stage K (zero-padded rows)
  for (int u = tid; u < NP * 4; u += 512) {
    const int key = u >> 2, j = u & 3;
    f16x8 val = {0, 0, 0, 0, 0, 0, 0, 0};
    if (key < N_TOK) val = *(const f16x8*)(Kg + key * HD + j * 8);
    *(f16x8*)&Ks[key][j * 8] = val;
  }
  // stage V transposed; zero-fill tail cols
  for (int i = tid; i < N_TOK * 16; i += 512) {
    const int n = i >> 4, dp = i & 15;
    const f16x2 v2 = *(const f16x2*)(Vg + n * HD + dp * 2);
    Vt[2 * dp][n] = v2.x;
    Vt[2 * dp + 1][n] = v2.y;
  }
  for (int i = tid; i < HD * 13; i += 512) Vt[i / 13][N_TOK + i % 13] = (f16)0;
  __syncthreads();

  const int w = b & (NW - 1);
  const f32x4 zero = {0.f, 0.f, 0.f, 0.f};

  for (int qt = wave; qt < NP / 16; qt += 8) {
    const int q = qt * 16 + c;
    const int qrow = (q < N_TOK) ? q : (N_TOK - 1);
    const f16x8 qf = *(const f16x8*)(Qg + qrow * HD + g * 8);
    const f16* cmrow = CMB + ((long)(w * HEADS + h) * N_TOK + qrow) * NP;

    f32x4 acc0 = zero, acc1 = zero;
    float lsum = 0.f;

    for (int kt = 0; kt < NP / 32; ++kt) {
      const f16x8 kf0 = *(const f16x8*)&Ks[32 * kt + c][g * 8];
      const f16x8 kf1 = *(const f16x8*)&Ks[32 * kt + 16 + c][g * 8];
      const f16x4 cm0 = *(const f16x4*)(cmrow + 32 * kt + 4 * g);
      const f16x4 cm1 = *(const f16x4*)(cmrow + 32 * kt + 16 + 4 * g);

      const f32x4 s0 = __builtin_amdgcn_mfma_f32_16x16x32_f16(kf0, qf, zero, 0, 0, 0);
      const f32x4 s1 = __builtin_amdgcn_mfma_f32_16x16x32_f16(kf1, qf, zero, 0, 0, 0);

      float p0[4], p1[4];
#pragma unroll
      for (int r = 0; r < 4; ++r) {
        p0[r] = __expf(s0[r] + (float)cm0[r]);
        p1[r] = __expf(s1[r] + (float)cm1[r]);
        lsum += p0[r] + p1[r];
      }
      // in-lane P fragment: slots 0-3 = keys 4g+r, slots 4-7 = keys 16+4g+r
      const f16x2 a0 = __builtin_bit_cast(f16x2, __builtin_amdgcn_cvt_pkrtz(p0[0], p0[1]));
      const f16x2 a1 = __builtin_bit_cast(f16x2, __builtin_amdgcn_cvt_pkrtz(p0[2], p0[3]));
      const f16x2 a2 = __builtin_bit_cast(f16x2, __builtin_amdgcn_cvt_pkrtz(p1[0], p1[1]));
      const f16x2 a3 = __builtin_bit_cast(f16x2, __builtin_amdgcn_cvt_pkrtz(p1[2], p1[3]));
      const f16x4 plo = __builtin_shufflevector(a0, a1, 0, 1, 2, 3);
      const f16x4 phi = __builtin_shufflevector(a2, a3, 0, 1, 2, 3);
      const f16x8 pf = __builtin_shufflevector(plo, phi, 0, 1, 2, 3, 4, 5, 6, 7);

      // V frags with matching key-slot offsets
      const f16x4 va0 = *(const f16x4*)&Vt[c][32 * kt + 4 * g];
      const f16x4 va1 = *(const f16x4*)&Vt[c][32 * kt + 16 + 4 * g];
      const f16x4 vb0 = *(const f16x4*)&Vt[16 + c][32 * kt + 4 * g];
      const f16x4 vb1 = *(const f16x4*)&Vt[16 + c][32 * kt + 16 + 4 * g];
      const f16x8 vf0 = __builtin_shufflevector(va0, va1, 0, 1, 2, 3, 4, 5, 6, 7);
      const f16x8 vf1 = __builtin_shufflevector(vb0, vb1, 0, 1, 2, 3, 4, 5, 6, 7);

      acc0 = __builtin_amdgcn_mfma_f32_16x16x32_f16(vf0, pf, acc0, 0, 0, 0);
      acc1 = __builtin_amdgcn_mfma_f32_16x16x32_f16(vf1, pf, acc1, 0, 0, 0);
    }

    lsum += __shfl_xor(lsum, 16);
    lsum += __shfl_xor(lsum, 32);
    const float inv = 1.f / lsum;

    if (q < N_TOK) {
      f16* orow = X2h + ((long)b * N_TOK + q) * C_DIM + h * HD;
      f16x4 o0, o1;
#pragma unroll
      for (int r = 0; r < 4; ++r) {
        o0[r] = (f16)(acc0[r] * inv);
        o1[r] = (f16)(acc1[r] * inv);
      }
      *(f16x4*)(orow + 4 * g) = o0;
      *(f16x4*)(orow + 16 + 4 * g) = o1;
    }
  }
}

// ---------------------------------------------------------------------------
// Kernel C: MFMA proj. out = X2h @ wt_proj + b_proj (f32), LDS-bounced
// coalesced f32x4 stores.
// ---------------------------------------------------------------------------
__global__ __launch_bounds__(256) void proj_mfma_kernel(
    const f16* __restrict__ X2h, const f16* __restrict__ wt,
    const float* __restrict__ bias, float* __restrict__ out) {
  __shared__ float shp[4][16][100];
  const int tid = threadIdx.x;
  const int wave = tid >> 6, lane = tid & 63;
  const int c = lane & 15, g = lane >> 4;
  const long rowTile = (long)blockIdx.x * 64 + wave * 16;
  const long arow = rowTile + c;

  f16x8 af[3];
#pragma unroll
  for (int ks = 0; ks < 3; ++ks)
    af[ks] = *(const f16x8*)(X2h + arow * 96 + ks * 32 + g * 8);

  const f32x4 zero = {0.f, 0.f, 0.f, 0.f};
#pragma unroll
  for (int ct = 0; ct < 6; ++ct) {
    f32x4 acc = zero;
#pragma unroll
    for (int ks = 0; ks < 3; ++ks) {
      const f16x8 bf = *(const f16x8*)(wt + (ct * 16 + c) * 96 + ks * 32 + g * 8);
      acc = __builtin_amdgcn_mfma_f32_16x16x32_f16(af[ks], bf, acc, 0, 0, 0);
    }
    const float bv = bias[ct * 16 + c];
#pragma unroll
    for (int r = 0; r < 4; ++r)
      shp[wave][4 * g + r][ct * 16 + c] = acc[r] + bv;
  }
  __builtin_amdgcn_wave_barrier();
#pragma unroll
  for (int i = 0; i < 6; ++i) {
    const int u = lane + 64 * i;
    const int row = u / 24, ch = u % 24;
    const float4 v = *(const float4*)&shp[wave][row][ch * 4];
    *(float4*)(out + (rowTile + row) * 96 + ch * 4) = v;
  }
}

// ---------------------------------------------------------------------------
extern "C" void kernel_launch(void* const* d_in, const int* in_sizes, int n_in,
                              void* d_out, int out_size, void* d_ws, size_t ws_size,
                              hipStream_t stream) {
  const float* x          = (const float*)d_in[0];
  const float* mask       = (const float*)d_in[1];
  const float* w_qkv      = (const float*)d_in[2];
  const float* b_qkv      = (const float*)d_in[3];
  const float* bias_table = (const float*)d_in[4];
  const float* w_proj     = (const float*)d_in[5];
  const float* b_proj     = (const float*)d_in[6];
  float* out = (float*)d_out;

  f16* Qh = (f16*)d_ws;
  f16* Kh = Qh + QKV_ELEMS;
  f16* Vh = Kh + QKV_ELEMS;
  f16* X2h = Vh + QKV_ELEMS;
  f16* CMB = X2h + X2_ELEMS;
  f16* WTQ = CMB + CMB_ELEMS;
  f16* WTP = WTQ + QKV_COLS * 96;

  const int cmbBlocks = (int)((CMB_ELEMS + 255) / 256);
  const int wBlocks = (QKV_COLS * 96 + 96 * 96 + 255) / 256;  // 144
  const int gemmBlocks = (B_SZ * N_TOK) / 64;                  // 1372

  wprep_kernel<<<wBlocks, 256, 0, stream>>>(w_qkv, w_proj, WTQ, WTP);
  cmb_kernel<<<cmbBlocks, 256, 0, stream>>>(mask, bias_table, CMB);
  qkv_mfma_kernel<<<gemmBlocks, 256, 0, stream>>>(x, WTQ, b_qkv, Qh, Kh, Vh);
  attn_kernel<<<B_SZ * HEADS, 512, 0, stream>>>(Qh, Kh, Vh, CMB, X2h);
  proj_mfma_kernel<<<gemmBlocks, 256, 0, stream>>>(X2h, WTP, b_proj, out);
}

// Round 7
// 210.544 us; speedup vs baseline: 1.8239x; 1.7971x over previous
//
#include <hip/hip_runtime.h>

#define N_TOK 343
#define NP 352        // padded tokens (22*16)
#define C_DIM 96
#define HEADS 3
#define HD 32
#define B_SZ 256
#define NW 32
#define QKV_COLS 288

#define QKV_ELEMS (B_SZ * HEADS * N_TOK * HD)  // 8429568
#define X2_ELEMS ((long)B_SZ * N_TOK * C_DIM)  // 8429568
#define CMB_ELEMS ((long)NW * HEADS * N_TOK * NP)

typedef _Float16 f16;
typedef _Float16 f16x2 __attribute__((ext_vector_type(2)));
typedef _Float16 f16x4 __attribute__((ext_vector_type(4)));
typedef _Float16 f16x8 __attribute__((ext_vector_type(8)));
typedef float f32x4 __attribute__((ext_vector_type(4)));

// ---------------------------------------------------------------------------
// Kernel W: transpose+cast weights to f16. wt_qkv[col][k], wt_proj[col][k].
// ---------------------------------------------------------------------------
__global__ __launch_bounds__(256) void wprep_kernel(
    const float* __restrict__ w_qkv, const float* __restrict__ w_proj,
    f16* __restrict__ wt_qkv, f16* __restrict__ wt_proj) {
  const int e = blockIdx.x * 256 + threadIdx.x;
  if (e < QKV_COLS * 96) {
    const int cc = e / 96, k = e % 96;
    wt_qkv[e] = (f16)w_qkv[k * QKV_COLS + cc];
  } else {
    const int e2 = e - QKV_COLS * 96;
    if (e2 < 96 * 96) {
      const int cc = e2 / 96, k = e2 % 96;
      wt_proj[e2] = (f16)w_proj[k * 96 + cc];
    }
  }
}

// ---------------------------------------------------------------------------
// Kernel P: fused bias+mask -> CMB[w][h][343][352] f16. Pad keys get -1000.
// ---------------------------------------------------------------------------
__global__ __launch_bounds__(256) void cmb_kernel(
    const float* __restrict__ mask, const float* __restrict__ bias_table,
    f16* __restrict__ cmb) {
  const long e = (long)blockIdx.x * 256 + threadIdx.x;
  if (e >= CMB_ELEMS) return;
  const int key = (int)(e % NP);
  const long rowid = e / NP;
  const int q = (int)(rowid % N_TOK);
  const int wh = (int)(rowid / N_TOK);
  const int h = wh % HEADS;
  const int w = wh / HEADS;
  float val;
  if (key < N_TOK) {
    const int bn = (q / 49) * 169 + ((q / 7) % 7) * 13 + (q % 7);
    const int bm = (key / 49) * 169 + ((key / 7) % 7) * 13 + (key % 7);
    val = bias_table[(bn - bm + 1098) * HEADS + h] +
          mask[((long)w * N_TOK + q) * N_TOK + key];
  } else {
    val = -1000.f;
  }
  cmb[e] = (f16)val;
}

// ---------------------------------------------------------------------------
// Kernel A: MFMA qkv. Block = 64 rows (4 waves x 16), 288 cols.
// All epilogues LDS-bounced to coalesced f16x8 stores (Q,K,V same layout).
// ---------------------------------------------------------------------------
__global__ __launch_bounds__(256) void qkv_mfma_kernel(
    const float* __restrict__ x, const f16* __restrict__ wt,
    const float* __restrict__ bias,
    f16* __restrict__ Q, f16* __restrict__ K, f16* __restrict__ V) {
  __shared__ f16 sh[4][16][40];  // per-wave transpose tile
  const int tid = threadIdx.x;
  const int wave = tid >> 6, lane = tid & 63;
  const int c = lane & 15, g = lane >> 4;
  const long rowTile = (long)blockIdx.x * 64 + wave * 16;
  const long arow = rowTile + c;

  // A-frags: x rows cast f32 -> f16
  f16x8 af[3];
#pragma unroll
  for (int ks = 0; ks < 3; ++ks) {
    const float* px = x + arow * 96 + ks * 32 + g * 8;
    const float4 lo = *(const float4*)px;
    const float4 hi = *(const float4*)(px + 4);
    f16x8 v;
    v[0] = (f16)lo.x; v[1] = (f16)lo.y; v[2] = (f16)lo.z; v[3] = (f16)lo.w;
    v[4] = (f16)hi.x; v[5] = (f16)hi.y; v[6] = (f16)hi.z; v[7] = (f16)hi.w;
    af[ks] = v;
  }

  // per-lane ids for the coalesced store (row = rowTile + lane/4)
  const int rowL = (int)rowTile + (lane >> 2);
  const int bL = rowL / N_TOK, nL = rowL % N_TOK;

  const f32x4 zero = {0.f, 0.f, 0.f, 0.f};
  const float scale = 0.17677669529663687f;  // hd^-0.5

#pragma unroll
  for (int p = 0; p < 9; ++p) {              // pair p: cts 2p, 2p+1
    const int which = p / 3;                 // 0=q 1=k 2=v
    const int h = p % 3;
    const float mult = (which == 0) ? scale : 1.0f;
#pragma unroll
    for (int e = 0; e < 2; ++e) {
      const int ct = 2 * p + e;
      f32x4 acc = zero;
#pragma unroll
      for (int ks = 0; ks < 3; ++ks) {
        const f16x8 bf = *(const f16x8*)(wt + (ct * 16 + c) * 96 + ks * 32 + g * 8);
        acc = __builtin_amdgcn_mfma_f32_16x16x32_f16(af[ks], bf, acc, 0, 0, 0);
      }
      const float bv = bias[ct * 16 + c];
#pragma unroll
      for (int r = 0; r < 4; ++r)
        sh[wave][4 * g + r][(e << 4) + c] = (f16)((acc[r] + bv) * mult);
    }
    __builtin_amdgcn_wave_barrier();
    const f16x8 po = *(const f16x8*)&sh[wave][lane >> 2][(lane & 3) * 8];
    __builtin_amdgcn_wave_barrier();
    f16* dst = (which == 0) ? Q : (which == 1) ? K : V;
    *(f16x8*)(dst + (((long)bL * HEADS + h) * N_TOK + nL) * HD + (lane & 3) * 8) = po;
  }
}

// ---------------------------------------------------------------------------
// Kernel B: MFMA attention v3b. K+V staged in LDS (51KB -> 3 blocks/CU).
// In-lane P via k-slot permutation: slot j <-> keys {4g+j | 16+4g+(j-4)};
// V frags read at matching offsets. No P buffer, no per-K-step barriers.
// NOTE: no min-waves launch-bounds hint — R5/R6's (512,6) squeezed the
// allocator to 40 VGPRs and spilled the K-loop to scratch (590 MB/dispatch
// of HBM traffic = the entire 217 us).
// ---------------------------------------------------------------------------
__global__ __launch_bounds__(512) void attn_kernel(
    const f16* __restrict__ Qh, const f16* __restrict__ Kh,
    const f16* __restrict__ Vh, const f16* __restrict__ CMB,
    f16* __restrict__ X2h) {
  __shared__ f16 Ks[NP][40];   // 80B stride: 2-way bank aliasing (free)
  __shared__ f16 Vt[HD][356];  // 712B stride: even-bank spread

  const int blk = blockIdx.x;
  const int b = blk / HEADS;
  const int h = blk % HEADS;
  const int tid = threadIdx.x;
  const int wave = tid >> 6;
  const int lane = tid & 63;
  const int c = lane & 15;
  const int g = lane >> 4;

  const f16* Kg = Kh + (long)blk * (N_TOK * HD);
  const f16* Vg = Vh + (long)blk * (N_TOK * HD);
  const f16* Qg = Qh + (long)blk * (N_TOK * HD);

  // stage K (zero-padded rows)
  for (int u = tid; u < NP * 4; u += 512) {
    const int key = u >> 2, j = u & 3;
    f16x8 val = {0, 0, 0, 0, 0, 0, 0, 0};
    if (key < N_TOK) val = *(const f16x8*)(Kg + key * HD + j * 8);
    *(f16x8*)&Ks[key][j * 8] = val;
  }
  // stage V transposed; zero-fill tail cols
  for (int i = tid; i < N_TOK * 16; i += 512) {
    const int n = i >> 4, dp = i & 15;
    const f16x2 v2 = *(const f16x2*)(Vg + n * HD + dp * 2);
    Vt[2 * dp][n] = v2.x;
    Vt[2 * dp + 1][n] = v2.y;
  }
  for (int i = tid; i < HD * 13; i += 512) Vt[i / 13][N_TOK + i % 13] = (f16)0;
  __syncthreads();

  const int w = b & (NW - 1);
  const f32x4 zero = {0.f, 0.f, 0.f, 0.f};

  for (int qt = wave; qt < NP / 16; qt += 8) {
    const int q = qt * 16 + c;
    const int qrow = (q < N_TOK) ? q : (N_TOK - 1);
    const f16x8 qf = *(const f16x8*)(Qg + qrow * HD + g * 8);
    const f16* cmrow = CMB + ((long)(w * HEADS + h) * N_TOK + qrow) * NP;

    f32x4 acc0 = zero, acc1 = zero;
    float lsum = 0.f;

    for (int kt = 0; kt < NP / 32; ++kt) {
      const f16x8 kf0 = *(const f16x8*)&Ks[32 * kt + c][g * 8];
      const f16x8 kf1 = *(const f16x8*)&Ks[32 * kt + 16 + c][g * 8];
      const f16x4 cm0 = *(const f16x4*)(cmrow + 32 * kt + 4 * g);
      const f16x4 cm1 = *(const f16x4*)(cmrow + 32 * kt + 16 + 4 * g);

      const f32x4 s0 = __builtin_amdgcn_mfma_f32_16x16x32_f16(kf0, qf, zero, 0, 0, 0);
      const f32x4 s1 = __builtin_amdgcn_mfma_f32_16x16x32_f16(kf1, qf, zero, 0, 0, 0);

      float p0[4], p1[4];
#pragma unroll
      for (int r = 0; r < 4; ++r) {
        p0[r] = __expf(s0[r] + (float)cm0[r]);
        p1[r] = __expf(s1[r] + (float)cm1[r]);
        lsum += p0[r] + p1[r];
      }
      // in-lane P fragment: slots 0-3 = keys 4g+r, slots 4-7 = keys 16+4g+r
      const f16x2 a0 = __builtin_bit_cast(f16x2, __builtin_amdgcn_cvt_pkrtz(p0[0], p0[1]));
      const f16x2 a1 = __builtin_bit_cast(f16x2, __builtin_amdgcn_cvt_pkrtz(p0[2], p0[3]));
      const f16x2 a2 = __builtin_bit_cast(f16x2, __builtin_amdgcn_cvt_pkrtz(p1[0], p1[1]));
      const f16x2 a3 = __builtin_bit_cast(f16x2, __builtin_amdgcn_cvt_pkrtz(p1[2], p1[3]));
      const f16x4 plo = __builtin_shufflevector(a0, a1, 0, 1, 2, 3);
      const f16x4 phi = __builtin_shufflevector(a2, a3, 0, 1, 2, 3);
      const f16x8 pf = __builtin_shufflevector(plo, phi, 0, 1, 2, 3, 4, 5, 6, 7);

      // V frags with matching key-slot offsets
      const f16x4 va0 = *(const f16x4*)&Vt[c][32 * kt + 4 * g];
      const f16x4 va1 = *(const f16x4*)&Vt[c][32 * kt + 16 + 4 * g];
      const f16x4 vb0 = *(const f16x4*)&Vt[16 + c][32 * kt + 4 * g];
      const f16x4 vb1 = *(const f16x4*)&Vt[16 + c][32 * kt + 16 + 4 * g];
      const f16x8 vf0 = __builtin_shufflevector(va0, va1, 0, 1, 2, 3, 4, 5, 6, 7);
      const f16x8 vf1 = __builtin_shufflevector(vb0, vb1, 0, 1, 2, 3, 4, 5, 6, 7);

      acc0 = __builtin_amdgcn_mfma_f32_16x16x32_f16(vf0, pf, acc0, 0, 0, 0);
      acc1 = __builtin_amdgcn_mfma_f32_16x16x32_f16(vf1, pf, acc1, 0, 0, 0);
    }

    lsum += __shfl_xor(lsum, 16);
    lsum += __shfl_xor(lsum, 32);
    const float inv = 1.f / lsum;

    if (q < N_TOK) {
      f16* orow = X2h + ((long)b * N_TOK + q) * C_DIM + h * HD;
      f16x4 o0, o1;
#pragma unroll
      for (int r = 0; r < 4; ++r) {
        o0[r] = (f16)(acc0[r] * inv);
        o1[r] = (f16)(acc1[r] * inv);
      }
      *(f16x4*)(orow + 4 * g) = o0;
      *(f16x4*)(orow + 16 + 4 * g) = o1;
    }
  }
}

// ---------------------------------------------------------------------------
// Kernel C: MFMA proj. out = X2h @ wt_proj + b_proj (f32), LDS-bounced
// coalesced f32x4 stores.
// ---------------------------------------------------------------------------
__global__ __launch_bounds__(256) void proj_mfma_kernel(
    const f16* __restrict__ X2h, const f16* __restrict__ wt,
    const float* __restrict__ bias, float* __restrict__ out) {
  __shared__ float shp[4][16][100];
  const int tid = threadIdx.x;
  const int wave = tid >> 6, lane = tid & 63;
  const int c = lane & 15, g = lane >> 4;
  const long rowTile = (long)blockIdx.x * 64 + wave * 16;
  const long arow = rowTile + c;

  f16x8 af[3];
#pragma unroll
  for (int ks = 0; ks < 3; ++ks)
    af[ks] = *(const f16x8*)(X2h + arow * 96 + ks * 32 + g * 8);

  const f32x4 zero = {0.f, 0.f, 0.f, 0.f};
#pragma unroll
  for (int ct = 0; ct < 6; ++ct) {
    f32x4 acc = zero;
#pragma unroll
    for (int ks = 0; ks < 3; ++ks) {
      const f16x8 bf = *(const f16x8*)(wt + (ct * 16 + c) * 96 + ks * 32 + g * 8);
      acc = __builtin_amdgcn_mfma_f32_16x16x32_f16(af[ks], bf, acc, 0, 0, 0);
    }
    const float bv = bias[ct * 16 + c];
#pragma unroll
    for (int r = 0; r < 4; ++r)
      shp[wave][4 * g + r][ct * 16 + c] = acc[r] + bv;
  }
  __builtin_amdgcn_wave_barrier();
#pragma unroll
  for (int i = 0; i < 6; ++i) {
    const int u = lane + 64 * i;
    const int row = u / 24, ch = u % 24;
    const float4 v = *(const float4*)&shp[wave][row][ch * 4];
    *(float4*)(out + (rowTile + row) * 96 + ch * 4) = v;
  }
}

// ---------------------------------------------------------------------------
extern "C" void kernel_launch(void* const* d_in, const int* in_sizes, int n_in,
                              void* d_out, int out_size, void* d_ws, size_t ws_size,
                              hipStream_t stream) {
  const float* x          = (const float*)d_in[0];
  const float* mask       = (const float*)d_in[1];
  const float* w_qkv      = (const float*)d_in[2];
  const float* b_qkv      = (const float*)d_in[3];
  const float* bias_table = (const float*)d_in[4];
  const float* w_proj     = (const float*)d_in[5];
  const float* b_proj     = (const float*)d_in[6];
  float* out = (float*)d_out;

  f16* Qh = (f16*)d_ws;
  f16* Kh = Qh + QKV_ELEMS;
  f16* Vh = Kh + QKV_ELEMS;
  f16* X2h = Vh + QKV_ELEMS;
  f16* CMB = X2h + X2_ELEMS;
  f16* WTQ = CMB + CMB_ELEMS;
  f16* WTP = WTQ + QKV_COLS * 96;

  const int cmbBlocks = (int)((CMB_ELEMS + 255) / 256);
  const int wBlocks = (QKV_COLS * 96 + 96 * 96 + 255) / 256;  // 144
  const int gemmBlocks = (B_SZ * N_TOK) / 64;                  // 1372

  wprep_kernel<<<wBlocks, 256, 0, stream>>>(w_qkv, w_proj, WTQ, WTP);
  cmb_kernel<<<cmbBlocks, 256, 0, stream>>>(mask, bias_table, CMB);
  qkv_mfma_kernel<<<gemmBlocks, 256, 0, stream>>>(x, WTQ, b_qkv, Qh, Kh, Vh);
  attn_kernel<<<B_SZ * HEADS, 512, 0, stream>>>(Qh, Kh, Vh, CMB, X2h);
  proj_mfma_kernel<<<gemmBlocks, 256, 0, stream>>>(X2h, WTP, b_proj, out);
}

// Round 8
// 200.583 us; speedup vs baseline: 1.9145x; 1.0497x over previous
//
#include <hip/hip_runtime.h>

#define N_TOK 343
#define NP 352        // padded tokens (22*16)
#define C_DIM 96
#define HEADS 3
#define HD 32
#define B_SZ 256
#define NW 32
#define QKV_COLS 288

#define QKV_ELEMS (B_SZ * HEADS * N_TOK * HD)  // 8429568
#define X2_ELEMS ((long)B_SZ * N_TOK * C_DIM)  // 8429568
#define CMB_ELEMS ((long)NW * HEADS * N_TOK * NP)

typedef _Float16 f16;
typedef _Float16 f16x2 __attribute__((ext_vector_type(2)));
typedef _Float16 f16x4 __attribute__((ext_vector_type(4)));
typedef _Float16 f16x8 __attribute__((ext_vector_type(8)));
typedef float f32x4 __attribute__((ext_vector_type(4)));

// ---------------------------------------------------------------------------
// Kernel W: transpose+cast weights to f16. wt_qkv[col][k], wt_proj[col][k].
// ---------------------------------------------------------------------------
__global__ __launch_bounds__(256) void wprep_kernel(
    const float* __restrict__ w_qkv, const float* __restrict__ w_proj,
    f16* __restrict__ wt_qkv, f16* __restrict__ wt_proj) {
  const int e = blockIdx.x * 256 + threadIdx.x;
  if (e < QKV_COLS * 96) {
    const int cc = e / 96, k = e % 96;
    wt_qkv[e] = (f16)w_qkv[k * QKV_COLS + cc];
  } else {
    const int e2 = e - QKV_COLS * 96;
    if (e2 < 96 * 96) {
      const int cc = e2 / 96, k = e2 % 96;
      wt_proj[e2] = (f16)w_proj[k * 96 + cc];
    }
  }
}

// ---------------------------------------------------------------------------
// Kernel P: fused (bias+mask)*log2e -> CMB[w][h][343][352] f16.
// 3D grid kills the 64-bit div/mod chains of the 1D version. exp2-ready.
// ---------------------------------------------------------------------------
__global__ __launch_bounds__(384) void cmb_kernel(
    const float* __restrict__ mask, const float* __restrict__ bias_table,
    f16* __restrict__ cmb) {
  const int q = blockIdx.x;      // 0..342
  const int w = blockIdx.y;      // 0..31
  const int key = threadIdx.x;   // 0..383 (use <352)
  if (key >= NP) return;
  const int bn = (q / 49) * 169 + ((q / 7) % 7) * 13 + (q % 7);
  const float LOG2E = 1.4426950408889634f;
  float mv = 0.f;
  int idx = 0;
  const bool valid = (key < N_TOK);
  if (valid) {
    const int bm = (key / 49) * 169 + ((key / 7) % 7) * 13 + (key % 7);
    idx = (bn - bm + 1098) * HEADS;
    mv = mask[((long)w * N_TOK + q) * N_TOK + key];
  }
#pragma unroll
  for (int h = 0; h < HEADS; ++h) {
    const float val = valid ? (bias_table[idx + h] + mv) * LOG2E : -14427.0f;
    cmb[((long)(w * HEADS + h) * N_TOK + q) * NP + key] = (f16)val;
  }
}

// ---------------------------------------------------------------------------
// Kernel A: MFMA qkv. Block = 64 rows (4 waves x 16), 288 cols.
// All epilogues LDS-bounced to coalesced f16x8 stores (Q,K,V same layout).
// Q pre-scaled by hd^-0.5 * log2(e)  (attn uses exp2).
// ---------------------------------------------------------------------------
__global__ __launch_bounds__(256) void qkv_mfma_kernel(
    const float* __restrict__ x, const f16* __restrict__ wt,
    const float* __restrict__ bias,
    f16* __restrict__ Q, f16* __restrict__ K, f16* __restrict__ V) {
  __shared__ f16 sh[4][16][40];  // per-wave transpose tile
  const int tid = threadIdx.x;
  const int wave = tid >> 6, lane = tid & 63;
  const int c = lane & 15, g = lane >> 4;
  const long rowTile = (long)blockIdx.x * 64 + wave * 16;
  const long arow = rowTile + c;

  // A-frags: x rows cast f32 -> f16
  f16x8 af[3];
#pragma unroll
  for (int ks = 0; ks < 3; ++ks) {
    const float* px = x + arow * 96 + ks * 32 + g * 8;
    const float4 lo = *(const float4*)px;
    const float4 hi = *(const float4*)(px + 4);
    f16x8 v;
    v[0] = (f16)lo.x; v[1] = (f16)lo.y; v[2] = (f16)lo.z; v[3] = (f16)lo.w;
    v[4] = (f16)hi.x; v[5] = (f16)hi.y; v[6] = (f16)hi.z; v[7] = (f16)hi.w;
    af[ks] = v;
  }

  // per-lane ids for the coalesced store (row = rowTile + lane/4)
  const int rowL = (int)rowTile + (lane >> 2);
  const int bL = rowL / N_TOK, nL = rowL % N_TOK;

  const f32x4 zero = {0.f, 0.f, 0.f, 0.f};
  const float scale = 0.17677669529663687f * 1.4426950408889634f;  // hd^-0.5 * log2e

#pragma unroll
  for (int p = 0; p < 9; ++p) {              // pair p: cts 2p, 2p+1
    const int which = p / 3;                 // 0=q 1=k 2=v
    const int h = p % 3;
    const float mult = (which == 0) ? scale : 1.0f;
#pragma unroll
    for (int e = 0; e < 2; ++e) {
      const int ct = 2 * p + e;
      f32x4 acc = zero;
#pragma unroll
      for (int ks = 0; ks < 3; ++ks) {
        const f16x8 bf = *(const f16x8*)(wt + (ct * 16 + c) * 96 + ks * 32 + g * 8);
        acc = __builtin_amdgcn_mfma_f32_16x16x32_f16(af[ks], bf, acc, 0, 0, 0);
      }
      const float bv = bias[ct * 16 + c];
#pragma unroll
      for (int r = 0; r < 4; ++r)
        sh[wave][4 * g + r][(e << 4) + c] = (f16)((acc[r] + bv) * mult);
    }
    __builtin_amdgcn_wave_barrier();
    const f16x8 po = *(const f16x8*)&sh[wave][lane >> 2][(lane & 3) * 8];
    __builtin_amdgcn_wave_barrier();
    f16* dst = (which == 0) ? Q : (which == 1) ? K : V;
    *(f16x8*)(dst + (((long)bL * HEADS + h) * N_TOK + nL) * HD + (lane & 3) * 8) = po;
  }
}

// ---------------------------------------------------------------------------
// Kernel B: MFMA attention v4. 4-wave (256-thr) blocks: 51KB LDS -> 3
// blocks/CU -> all 768 blocks co-resident (no tail; R7 had 1.5 rounds).
// In-lane P via k-slot permutation; cm prefetched one K-step ahead;
// exp2 (log2e pre-folded into Q scale and CMB).
// NO min-waves launch-bounds hint (R5/R6 spill lesson).
// ---------------------------------------------------------------------------
__global__ __launch_bounds__(256) void attn_kernel(
    const f16* __restrict__ Qh, const f16* __restrict__ Kh,
    const f16* __restrict__ Vh, const f16* __restrict__ CMB,
    f16* __restrict__ X2h) {
  __shared__ f16 Ks[NP][40];   // 80B stride: 2-way bank aliasing (free)
  __shared__ f16 Vt[HD][356];  // 712B stride: even-bank spread

  const int blk = blockIdx.x;
  const int b = blk / HEADS;
  const int h = blk % HEADS;
  const int tid = threadIdx.x;
  const int wave = tid >> 6;
  const int lane = tid & 63;
  const int c = lane & 15;
  const int g = lane >> 4;

  const f16* Kg = Kh + (long)blk * (N_TOK * HD);
  const f16* Vg = Vh + (long)blk * (N_TOK * HD);
  const f16* Qg = Qh + (long)blk * (N_TOK * HD);

  // stage K (zero-padded rows)
  for (int u = tid; u < NP * 4; u += 256) {
    const int key = u >> 2, j = u & 3;
    f16x8 val = {0, 0, 0, 0, 0, 0, 0, 0};
    if (key < N_TOK) val = *(const f16x8*)(Kg + key * HD + j * 8);
    *(f16x8*)&Ks[key][j * 8] = val;
  }
  // stage V transposed; zero-fill tail cols
  for (int i = tid; i < N_TOK * 16; i += 256) {
    const int n = i >> 4, dp = i & 15;
    const f16x2 v2 = *(const f16x2*)(Vg + n * HD + dp * 2);
    Vt[2 * dp][n] = v2.x;
    Vt[2 * dp + 1][n] = v2.y;
  }
  for (int i = tid; i < HD * 13; i += 256) Vt[i / 13][N_TOK + i % 13] = (f16)0;
  __syncthreads();

  const int w = b & (NW - 1);
  const f32x4 zero = {0.f, 0.f, 0.f, 0.f};

  for (int qt = wave; qt < NP / 16; qt += 4) {
    const int q = qt * 16 + c;
    const int qrow = (q < N_TOK) ? q : (N_TOK - 1);
    const f16x8 qf = *(const f16x8*)(Qg + qrow * HD + g * 8);
    const f16* cmrow = CMB + ((long)(w * HEADS + h) * N_TOK + qrow) * NP;

    f32x4 acc0 = zero, acc1 = zero;
    float lsum = 0.f;

    f16x4 cm0 = *(const f16x4*)(cmrow + 4 * g);
    f16x4 cm1 = *(const f16x4*)(cmrow + 16 + 4 * g);

    for (int kt = 0; kt < NP / 32; ++kt) {
      f16x4 ncm0, ncm1;
      if (kt < NP / 32 - 1) {
        ncm0 = *(const f16x4*)(cmrow + 32 * (kt + 1) + 4 * g);
        ncm1 = *(const f16x4*)(cmrow + 32 * (kt + 1) + 16 + 4 * g);
      }
      const f16x8 kf0 = *(const f16x8*)&Ks[32 * kt + c][g * 8];
      const f16x8 kf1 = *(const f16x8*)&Ks[32 * kt + 16 + c][g * 8];

      const f32x4 s0 = __builtin_amdgcn_mfma_f32_16x16x32_f16(kf0, qf, zero, 0, 0, 0);
      const f32x4 s1 = __builtin_amdgcn_mfma_f32_16x16x32_f16(kf1, qf, zero, 0, 0, 0);

      float p0[4], p1[4];
#pragma unroll
      for (int r = 0; r < 4; ++r) {
        p0[r] = __builtin_amdgcn_exp2f(s0[r] + (float)cm0[r]);
        p1[r] = __builtin_amdgcn_exp2f(s1[r] + (float)cm1[r]);
        lsum += p0[r] + p1[r];
      }
      // in-lane P fragment: slots 0-3 = keys 4g+r, slots 4-7 = keys 16+4g+r
      const f16x2 a0 = __builtin_bit_cast(f16x2, __builtin_amdgcn_cvt_pkrtz(p0[0], p0[1]));
      const f16x2 a1 = __builtin_bit_cast(f16x2, __builtin_amdgcn_cvt_pkrtz(p0[2], p0[3]));
      const f16x2 a2 = __builtin_bit_cast(f16x2, __builtin_amdgcn_cvt_pkrtz(p1[0], p1[1]));
      const f16x2 a3 = __builtin_bit_cast(f16x2, __builtin_amdgcn_cvt_pkrtz(p1[2], p1[3]));
      const f16x4 plo = __builtin_shufflevector(a0, a1, 0, 1, 2, 3);
      const f16x4 phi = __builtin_shufflevector(a2, a3, 0, 1, 2, 3);
      const f16x8 pf = __builtin_shufflevector(plo, phi, 0, 1, 2, 3, 4, 5, 6, 7);

      // V frags with matching key-slot offsets
      const f16x4 va0 = *(const f16x4*)&Vt[c][32 * kt + 4 * g];
      const f16x4 va1 = *(const f16x4*)&Vt[c][32 * kt + 16 + 4 * g];
      const f16x4 vb0 = *(const f16x4*)&Vt[16 + c][32 * kt + 4 * g];
      const f16x4 vb1 = *(const f16x4*)&Vt[16 + c][32 * kt + 16 + 4 * g];
      const f16x8 vf0 = __builtin_shufflevector(va0, va1, 0, 1, 2, 3, 4, 5, 6, 7);
      const f16x8 vf1 = __builtin_shufflevector(vb0, vb1, 0, 1, 2, 3, 4, 5, 6, 7);

      acc0 = __builtin_amdgcn_mfma_f32_16x16x32_f16(vf0, pf, acc0, 0, 0, 0);
      acc1 = __builtin_amdgcn_mfma_f32_16x16x32_f16(vf1, pf, acc1, 0, 0, 0);

      cm0 = ncm0;
      cm1 = ncm1;
    }

    lsum += __shfl_xor(lsum, 16);
    lsum += __shfl_xor(lsum, 32);
    const float inv = 1.f / lsum;

    if (q < N_TOK) {
      f16* orow = X2h + ((long)b * N_TOK + q) * C_DIM + h * HD;
      f16x4 o0, o1;
#pragma unroll
      for (int r = 0; r < 4; ++r) {
        o0[r] = (f16)(acc0[r] * inv);
        o1[r] = (f16)(acc1[r] * inv);
      }
      *(f16x4*)(orow + 4 * g) = o0;
      *(f16x4*)(orow + 16 + 4 * g) = o1;
    }
  }
}

// ---------------------------------------------------------------------------
// Kernel C: MFMA proj. out = X2h @ wt_proj + b_proj (f32), LDS-bounced
// coalesced f32x4 stores.
// ---------------------------------------------------------------------------
__global__ __launch_bounds__(256) void proj_mfma_kernel(
    const f16* __restrict__ X2h, const f16* __restrict__ wt,
    const float* __restrict__ bias, float* __restrict__ out) {
  __shared__ float shp[4][16][100];
  const int tid = threadIdx.x;
  const int wave = tid >> 6, lane = tid & 63;
  const int c = lane & 15, g = lane >> 4;
  const long rowTile = (long)blockIdx.x * 64 + wave * 16;
  const long arow = rowTile + c;

  f16x8 af[3];
#pragma unroll
  for (int ks = 0; ks < 3; ++ks)
    af[ks] = *(const f16x8*)(X2h + arow * 96 + ks * 32 + g * 8);

  const f32x4 zero = {0.f, 0.f, 0.f, 0.f};
#pragma unroll
  for (int ct = 0; ct < 6; ++ct) {
    f32x4 acc = zero;
#pragma unroll
    for (int ks = 0; ks < 3; ++ks) {
      const f16x8 bf = *(const f16x8*)(wt + (ct * 16 + c) * 96 + ks * 32 + g * 8);
      acc = __builtin_amdgcn_mfma_f32_16x16x32_f16(af[ks], bf, acc, 0, 0, 0);
    }
    const float bv = bias[ct * 16 + c];
#pragma unroll
    for (int r = 0; r < 4; ++r)
      shp[wave][4 * g + r][ct * 16 + c] = acc[r] + bv;
  }
  __builtin_amdgcn_wave_barrier();
#pragma unroll
  for (int i = 0; i < 6; ++i) {
    const int u = lane + 64 * i;
    const int row = u / 24, ch = u % 24;
    const float4 v = *(const float4*)&shp[wave][row][ch * 4];
    *(float4*)(out + (rowTile + row) * 96 + ch * 4) = v;
  }
}

// ---------------------------------------------------------------------------
extern "C" void kernel_launch(void* const* d_in, const int* in_sizes, int n_in,
                              void* d_out, int out_size, void* d_ws, size_t ws_size,
                              hipStream_t stream) {
  const float* x          = (const float*)d_in[0];
  const float* mask       = (const float*)d_in[1];
  const float* w_qkv      = (const float*)d_in[2];
  const float* b_qkv      = (const float*)d_in[3];
  const float* bias_table = (const float*)d_in[4];
  const float* w_proj     = (const float*)d_in[5];
  const float* b_proj     = (const float*)d_in[6];
  float* out = (float*)d_out;

  f16* Qh = (f16*)d_ws;
  f16* Kh = Qh + QKV_ELEMS;
  f16* Vh = Kh + QKV_ELEMS;
  f16* X2h = Vh + QKV_ELEMS;
  f16* CMB = X2h + X2_ELEMS;
  f16* WTQ = CMB + CMB_ELEMS;
  f16* WTP = WTQ + QKV_COLS * 96;

  const int wBlocks = (QKV_COLS * 96 + 96 * 96 + 255) / 256;  // 144
  const int gemmBlocks = (B_SZ * N_TOK) / 64;                  // 1372

  wprep_kernel<<<wBlocks, 256, 0, stream>>>(w_qkv, w_proj, WTQ, WTP);
  cmb_kernel<<<dim3(N_TOK, NW), 384, 0, stream>>>(mask, bias_table, CMB);
  qkv_mfma_kernel<<<gemmBlocks, 256, 0, stream>>>(x, WTQ, b_qkv, Qh, Kh, Vh);
  attn_kernel<<<B_SZ * HEADS, 256, 0, stream>>>(Qh, Kh, Vh, CMB, X2h);
  proj_mfma_kernel<<<gemmBlocks, 256, 0, stream>>>(X2h, WTP, b_proj, out);
}

// Round 9
// 200.156 us; speedup vs baseline: 1.9186x; 1.0021x over previous
//
#include <hip/hip_runtime.h>

#define N_TOK 343
#define NP 352        // padded tokens (22*16)
#define C_DIM 96
#define HEADS 3
#define HD 32
#define B_SZ 256
#define NW 32
#define QKV_COLS 288
#define NKT 11        // NP/32 k-steps

#define QKV_ELEMS (B_SZ * HEADS * N_TOK * HD)  // 8429568
#define X2_ELEMS ((long)B_SZ * N_TOK * C_DIM)  // 8429568
#define CMB_ELEMS ((long)NW * HEADS * N_TOK * NP)
#define WT_PITCH 104  // 16B-aligned row pitch for LDS weight tiles

typedef _Float16 f16;
typedef _Float16 f16x2 __attribute__((ext_vector_type(2)));
typedef _Float16 f16x4 __attribute__((ext_vector_type(4)));
typedef _Float16 f16x8 __attribute__((ext_vector_type(8)));
typedef float f32x4 __attribute__((ext_vector_type(4)));

// ---------------------------------------------------------------------------
// Kernel W: transpose+cast weights to f16. wt_qkv[col][k], wt_proj[col][k].
// ---------------------------------------------------------------------------
__global__ __launch_bounds__(256) void wprep_kernel(
    const float* __restrict__ w_qkv, const float* __restrict__ w_proj,
    f16* __restrict__ wt_qkv, f16* __restrict__ wt_proj) {
  const int e = blockIdx.x * 256 + threadIdx.x;
  if (e < QKV_COLS * 96) {
    const int cc = e / 96, k = e % 96;
    wt_qkv[e] = (f16)w_qkv[k * QKV_COLS + cc];
  } else {
    const int e2 = e - QKV_COLS * 96;
    if (e2 < 96 * 96) {
      const int cc = e2 / 96, k = e2 % 96;
      wt_proj[e2] = (f16)w_proj[k * 96 + cc];
    }
  }
}

// ---------------------------------------------------------------------------
// Kernel P: fused (bias+mask)*log2e -> CMB[w][h][343][352] f16.
// ---------------------------------------------------------------------------
__global__ __launch_bounds__(384) void cmb_kernel(
    const float* __restrict__ mask, const float* __restrict__ bias_table,
    f16* __restrict__ cmb) {
  const int q = blockIdx.x;      // 0..342
  const int w = blockIdx.y;      // 0..31
  const int key = threadIdx.x;   // 0..383 (use <352)
  if (key >= NP) return;
  const int bn = (q / 49) * 169 + ((q / 7) % 7) * 13 + (q % 7);
  const float LOG2E = 1.4426950408889634f;
  float mv = 0.f;
  int idx = 0;
  const bool valid = (key < N_TOK);
  if (valid) {
    const int bm = (key / 49) * 169 + ((key / 7) % 7) * 13 + (key % 7);
    idx = (bn - bm + 1098) * HEADS;
    mv = mask[((long)w * N_TOK + q) * N_TOK + key];
  }
#pragma unroll
  for (int h = 0; h < HEADS; ++h) {
    const float val = valid ? (bias_table[idx + h] + mv) * LOG2E : -14427.0f;
    cmb[((long)(w * HEADS + h) * N_TOK + q) * NP + key] = (f16)val;
  }
}

// ---------------------------------------------------------------------------
// Kernel A: MFMA qkv. Block = 128 rows (8 waves x 16), 288 cols.
// wt staged in LDS once per block (kills dependent global B-frag loads).
// Epilogues LDS-bounced to coalesced f16x8 stores.
// Q pre-scaled by hd^-0.5 * log2(e)  (attn uses exp2).
// ---------------------------------------------------------------------------
__global__ __launch_bounds__(512) void qkv_mfma_kernel(
    const float* __restrict__ x, const f16* __restrict__ wt,
    const float* __restrict__ bias,
    f16* __restrict__ Q, f16* __restrict__ K, f16* __restrict__ V) {
  __shared__ f16 wtL[QKV_COLS][WT_PITCH];  // 59904 B
  __shared__ f16 sh[8][16][40];            // 10240 B
  const int tid = threadIdx.x;
  const int wave = tid >> 6, lane = tid & 63;
  const int c = lane & 15, g = lane >> 4;
  const long rowTile = (long)blockIdx.x * 128 + wave * 16;
  const long arow = rowTile + c;

  // stage wt (288 rows x 12 f16x8 chunks), coalesced
  for (int u = tid; u < QKV_COLS * 12; u += 512) {
    const int r = u / 12, ch = u % 12;
    *(f16x8*)&wtL[r][ch * 8] = *(const f16x8*)(wt + r * 96 + ch * 8);
  }

  // A-frags: x rows cast f32 -> f16
  f16x8 af[3];
#pragma unroll
  for (int ks = 0; ks < 3; ++ks) {
    const float* px = x + arow * 96 + ks * 32 + g * 8;
    const float4 lo = *(const float4*)px;
    const float4 hi = *(const float4*)(px + 4);
    f16x8 v;
    v[0] = (f16)lo.x; v[1] = (f16)lo.y; v[2] = (f16)lo.z; v[3] = (f16)lo.w;
    v[4] = (f16)hi.x; v[5] = (f16)hi.y; v[6] = (f16)hi.z; v[7] = (f16)hi.w;
    af[ks] = v;
  }
  __syncthreads();

  // per-lane ids for the coalesced store (row = rowTile + lane/4)
  const int rowL = (int)rowTile + (lane >> 2);
  const int bL = rowL / N_TOK, nL = rowL % N_TOK;

  const f32x4 zero = {0.f, 0.f, 0.f, 0.f};
  const float scale = 0.17677669529663687f * 1.4426950408889634f;  // hd^-0.5 * log2e

#pragma unroll
  for (int p = 0; p < 9; ++p) {              // pair p: cts 2p, 2p+1
    const int which = p / 3;                 // 0=q 1=k 2=v
    const int h = p % 3;
    const float mult = (which == 0) ? scale : 1.0f;
#pragma unroll
    for (int e = 0; e < 2; ++e) {
      const int ct = 2 * p + e;
      f32x4 acc = zero;
#pragma unroll
      for (int ks = 0; ks < 3; ++ks) {
        const f16x8 bf = *(const f16x8*)&wtL[ct * 16 + c][ks * 32 + g * 8];
        acc = __builtin_amdgcn_mfma_f32_16x16x32_f16(af[ks], bf, acc, 0, 0, 0);
      }
      const float bv = bias[ct * 16 + c];
#pragma unroll
      for (int r = 0; r < 4; ++r)
        sh[wave][4 * g + r][(e << 4) + c] = (f16)((acc[r] + bv) * mult);
    }
    __builtin_amdgcn_wave_barrier();
    const f16x8 po = *(const f16x8*)&sh[wave][lane >> 2][(lane & 3) * 8];
    __builtin_amdgcn_wave_barrier();
    f16* dst = (which == 0) ? Q : (which == 1) ? K : V;
    *(f16x8*)(dst + (((long)bL * HEADS + h) * N_TOK + nL) * HD + (lane & 3) * 8) = po;
  }
}

// ---------------------------------------------------------------------------
// Kernel B: MFMA attention v5. 256-thr blocks, 51KB LDS (3 blocks/CU).
// ALL 11 k-steps' cm bulk-preloaded to registers per q-tile (one latency
// instead of eleven). In-lane P via k-slot permutation; exp2 path.
// NO min-waves launch-bounds hint (R5/R6 spill lesson).
// ---------------------------------------------------------------------------
__global__ __launch_bounds__(256) void attn_kernel(
    const f16* __restrict__ Qh, const f16* __restrict__ Kh,
    const f16* __restrict__ Vh, const f16* __restrict__ CMB,
    f16* __restrict__ X2h) {
  __shared__ f16 Ks[NP][40];   // 80B stride: 2-way bank aliasing (free)
  __shared__ f16 Vt[HD][356];  // 712B stride: odd word pitch, spread banks

  const int blk = blockIdx.x;
  const int b = blk / HEADS;
  const int h = blk % HEADS;
  const int tid = threadIdx.x;
  const int wave = tid >> 6;
  const int lane = tid & 63;
  const int c = lane & 15;
  const int g = lane >> 4;

  const f16* Kg = Kh + (long)blk * (N_TOK * HD);
  const f16* Vg = Vh + (long)blk * (N_TOK * HD);
  const f16* Qg = Qh + (long)blk * (N_TOK * HD);

  // stage K (zero-padded rows)
  for (int u = tid; u < NP * 4; u += 256) {
    const int key = u >> 2, j = u & 3;
    f16x8 val = {0, 0, 0, 0, 0, 0, 0, 0};
    if (key < N_TOK) val = *(const f16x8*)(Kg + key * HD + j * 8);
    *(f16x8*)&Ks[key][j * 8] = val;
  }
  // stage V transposed; zero-fill tail cols
  for (int i = tid; i < N_TOK * 16; i += 256) {
    const int n = i >> 4, dp = i & 15;
    const f16x2 v2 = *(const f16x2*)(Vg + n * HD + dp * 2);
    Vt[2 * dp][n] = v2.x;
    Vt[2 * dp + 1][n] = v2.y;
  }
  for (int i = tid; i < HD * 13; i += 256) Vt[i / 13][N_TOK + i % 13] = (f16)0;
  __syncthreads();

  const int w = b & (NW - 1);
  const f32x4 zero = {0.f, 0.f, 0.f, 0.f};

  for (int qt = wave; qt < NP / 16; qt += 4) {
    const int q = qt * 16 + c;
    const int qrow = (q < N_TOK) ? q : (N_TOK - 1);
    const f16* cmrow = CMB + ((long)(w * HEADS + h) * N_TOK + qrow) * NP;

    // bulk cm preload: all 11 k-steps, issued back-to-back (one latency)
    f16x4 cmA[NKT], cmB[NKT];
#pragma unroll
    for (int kt = 0; kt < NKT; ++kt) {
      cmA[kt] = *(const f16x4*)(cmrow + 32 * kt + 4 * g);
      cmB[kt] = *(const f16x4*)(cmrow + 32 * kt + 16 + 4 * g);
    }
    const f16x8 qf = *(const f16x8*)(Qg + qrow * HD + g * 8);

    f32x4 acc0 = zero, acc1 = zero;
    float lsum = 0.f;

#pragma unroll
    for (int kt = 0; kt < NKT; ++kt) {
      const f16x8 kf0 = *(const f16x8*)&Ks[32 * kt + c][g * 8];
      const f16x8 kf1 = *(const f16x8*)&Ks[32 * kt + 16 + c][g * 8];

      const f32x4 s0 = __builtin_amdgcn_mfma_f32_16x16x32_f16(kf0, qf, zero, 0, 0, 0);
      const f32x4 s1 = __builtin_amdgcn_mfma_f32_16x16x32_f16(kf1, qf, zero, 0, 0, 0);

      float p0[4], p1[4];
#pragma unroll
      for (int r = 0; r < 4; ++r) {
        p0[r] = __builtin_amdgcn_exp2f(s0[r] + (float)cmA[kt][r]);
        p1[r] = __builtin_amdgcn_exp2f(s1[r] + (float)cmB[kt][r]);
        lsum += p0[r] + p1[r];
      }
      // in-lane P fragment: slots 0-3 = keys 4g+r, slots 4-7 = keys 16+4g+r
      const f16x2 a0 = __builtin_bit_cast(f16x2, __builtin_amdgcn_cvt_pkrtz(p0[0], p0[1]));
      const f16x2 a1 = __builtin_bit_cast(f16x2, __builtin_amdgcn_cvt_pkrtz(p0[2], p0[3]));
      const f16x2 a2 = __builtin_bit_cast(f16x2, __builtin_amdgcn_cvt_pkrtz(p1[0], p1[1]));
      const f16x2 a3 = __builtin_bit_cast(f16x2, __builtin_amdgcn_cvt_pkrtz(p1[2], p1[3]));
      const f16x4 plo = __builtin_shufflevector(a0, a1, 0, 1, 2, 3);
      const f16x4 phi = __builtin_shufflevector(a2, a3, 0, 1, 2, 3);
      const f16x8 pf = __builtin_shufflevector(plo, phi, 0, 1, 2, 3, 4, 5, 6, 7);

      // V frags with matching key-slot offsets
      const f16x4 va0 = *(const f16x4*)&Vt[c][32 * kt + 4 * g];
      const f16x4 va1 = *(const f16x4*)&Vt[c][32 * kt + 16 + 4 * g];
      const f16x4 vb0 = *(const f16x4*)&Vt[16 + c][32 * kt + 4 * g];
      const f16x4 vb1 = *(const f16x4*)&Vt[16 + c][32 * kt + 16 + 4 * g];
      const f16x8 vf0 = __builtin_shufflevector(va0, va1, 0, 1, 2, 3, 4, 5, 6, 7);
      const f16x8 vf1 = __builtin_shufflevector(vb0, vb1, 0, 1, 2, 3, 4, 5, 6, 7);

      acc0 = __builtin_amdgcn_mfma_f32_16x16x32_f16(vf0, pf, acc0, 0, 0, 0);
      acc1 = __builtin_amdgcn_mfma_f32_16x16x32_f16(vf1, pf, acc1, 0, 0, 0);
    }

    lsum += __shfl_xor(lsum, 16);
    lsum += __shfl_xor(lsum, 32);
    const float inv = 1.f / lsum;

    if (q < N_TOK) {
      f16* orow = X2h + ((long)b * N_TOK + q) * C_DIM + h * HD;
      f16x4 o0, o1;
#pragma unroll
      for (int r = 0; r < 4; ++r) {
        o0[r] = (f16)(acc0[r] * inv);
        o1[r] = (f16)(acc1[r] * inv);
      }
      *(f16x4*)(orow + 4 * g) = o0;
      *(f16x4*)(orow + 16 + 4 * g) = o1;
    }
  }
}

// ---------------------------------------------------------------------------
// Kernel C: MFMA proj. out = X2h @ wt_proj + b_proj (f32). wt in LDS;
// LDS-bounced coalesced f32x4 stores.
// ---------------------------------------------------------------------------
__global__ __launch_bounds__(256) void proj_mfma_kernel(
    const f16* __restrict__ X2h, const f16* __restrict__ wt,
    const float* __restrict__ bias, float* __restrict__ out) {
  __shared__ f16 wtL[C_DIM][WT_PITCH];  // 19968 B
  __shared__ float shp[4][16][100];     // 25600 B
  const int tid = threadIdx.x;
  const int wave = tid >> 6, lane = tid & 63;
  const int c = lane & 15, g = lane >> 4;
  const long rowTile = (long)blockIdx.x * 64 + wave * 16;
  const long arow = rowTile + c;

  for (int u = tid; u < C_DIM * 12; u += 256) {
    const int r = u / 12, ch = u % 12;
    *(f16x8*)&wtL[r][ch * 8] = *(const f16x8*)(wt + r * 96 + ch * 8);
  }

  f16x8 af[3];
#pragma unroll
  for (int ks = 0; ks < 3; ++ks)
    af[ks] = *(const f16x8*)(X2h + arow * 96 + ks * 32 + g * 8);
  __syncthreads();

  const f32x4 zero = {0.f, 0.f, 0.f, 0.f};
#pragma unroll
  for (int ct = 0; ct < 6; ++ct) {
    f32x4 acc = zero;
#pragma unroll
    for (int ks = 0; ks < 3; ++ks) {
      const f16x8 bf = *(const f16x8*)&wtL[ct * 16 + c][ks * 32 + g * 8];
      acc = __builtin_amdgcn_mfma_f32_16x16x32_f16(af[ks], bf, acc, 0, 0, 0);
    }
    const float bv = bias[ct * 16 + c];
#pragma unroll
    for (int r = 0; r < 4; ++r)
      shp[wave][4 * g + r][ct * 16 + c] = acc[r] + bv;
  }
  __builtin_amdgcn_wave_barrier();
#pragma unroll
  for (int i = 0; i < 6; ++i) {
    const int u = lane + 64 * i;
    const int row = u / 24, ch = u % 24;
    const float4 v = *(const float4*)&shp[wave][row][ch * 4];
    *(float4*)(out + (rowTile + row) * 96 + ch * 4) = v;
  }
}

// ---------------------------------------------------------------------------
extern "C" void kernel_launch(void* const* d_in, const int* in_sizes, int n_in,
                              void* d_out, int out_size, void* d_ws, size_t ws_size,
                              hipStream_t stream) {
  const float* x          = (const float*)d_in[0];
  const float* mask       = (const float*)d_in[1];
  const float* w_qkv      = (const float*)d_in[2];
  const float* b_qkv      = (const float*)d_in[3];
  const float* bias_table = (const float*)d_in[4];
  const float* w_proj     = (const float*)d_in[5];
  const float* b_proj     = (const float*)d_in[6];
  float* out = (float*)d_out;

  f16* Qh = (f16*)d_ws;
  f16* Kh = Qh + QKV_ELEMS;
  f16* Vh = Kh + QKV_ELEMS;
  f16* X2h = Vh + QKV_ELEMS;
  f16* CMB = X2h + X2_ELEMS;
  f16* WTQ = CMB + CMB_ELEMS;
  f16* WTP = WTQ + QKV_COLS * 96;

  const int wBlocks = (QKV_COLS * 96 + 96 * 96 + 255) / 256;   // 144
  const int qkvBlocks = (B_SZ * N_TOK) / 128;                   // 686
  const int projBlocks = (B_SZ * N_TOK) / 64;                   // 1372

  wprep_kernel<<<wBlocks, 256, 0, stream>>>(w_qkv, w_proj, WTQ, WTP);
  cmb_kernel<<<dim3(N_TOK, NW), 384, 0, stream>>>(mask, bias_table, CMB);
  qkv_mfma_kernel<<<qkvBlocks, 512, 0, stream>>>(x, WTQ, b_qkv, Qh, Kh, Vh);
  attn_kernel<<<B_SZ * HEADS, 256, 0, stream>>>(Qh, Kh, Vh, CMB, X2h);
  proj_mfma_kernel<<<projBlocks, 256, 0, stream>>>(X2h, WTP, b_proj, out);
}

// Round 11
// 187.035 us; speedup vs baseline: 2.0532x; 1.0702x over previous
//
#include <hip/hip_runtime.h>

#define N_TOK 343
#define NP 352        // padded tokens (22*16)
#define C_DIM 96
#define HEADS 3
#define HD 32
#define B_SZ 256
#define NW 32
#define QKV_COLS 288
#define NKT 11        // NP/32 k-steps

#define QKV_ELEMS (B_SZ * HEADS * N_TOK * HD)  // 8429568
#define X2_ELEMS ((long)B_SZ * N_TOK * C_DIM)  // 8429568
#define CMB_ELEMS ((long)NW * HEADS * N_TOK * NP)
#define VTG_ELEMS ((long)B_SZ * HEADS * HD * NP)
#define WT_PITCH 104  // 16B-aligned row pitch for LDS weight tiles

typedef _Float16 f16;
typedef _Float16 f16x2 __attribute__((ext_vector_type(2)));
typedef _Float16 f16x4 __attribute__((ext_vector_type(4)));
typedef _Float16 f16x8 __attribute__((ext_vector_type(8)));
typedef float f32x4 __attribute__((ext_vector_type(4)));

// ---------------------------------------------------------------------------
// Kernel W: transpose+cast weights to f16. wt_qkv[col][k], wt_proj[col][k].
// ---------------------------------------------------------------------------
__global__ __launch_bounds__(256) void wprep_kernel(
    const float* __restrict__ w_qkv, const float* __restrict__ w_proj,
    f16* __restrict__ wt_qkv, f16* __restrict__ wt_proj) {
  const int e = blockIdx.x * 256 + threadIdx.x;
  if (e < QKV_COLS * 96) {
    const int cc = e / 96, k = e % 96;
    wt_qkv[e] = (f16)w_qkv[k * QKV_COLS + cc];
  } else {
    const int e2 = e - QKV_COLS * 96;
    if (e2 < 96 * 96) {
      const int cc = e2 / 96, k = e2 % 96;
      wt_proj[e2] = (f16)w_proj[k * 96 + cc];
    }
  }
}

// ---------------------------------------------------------------------------
// Kernel P: fused (bias+mask)*log2e -> CMB[w][h][343][352] f16.
// ---------------------------------------------------------------------------
__global__ __launch_bounds__(384) void cmb_kernel(
    const float* __restrict__ mask, const float* __restrict__ bias_table,
    f16* __restrict__ cmb) {
  const int q = blockIdx.x;      // 0..342
  const int w = blockIdx.y;      // 0..31
  const int key = threadIdx.x;   // 0..383 (use <352)
  if (key >= NP) return;
  const int bn = (q / 49) * 169 + ((q / 7) % 7) * 13 + (q % 7);
  const float LOG2E = 1.4426950408889634f;
  float mv = 0.f;
  int idx = 0;
  const bool valid = (key < N_TOK);
  if (valid) {
    const int bm = (key / 49) * 169 + ((key / 7) % 7) * 13 + (key % 7);
    idx = (bn - bm + 1098) * HEADS;
    mv = mask[((long)w * N_TOK + q) * N_TOK + key];
  }
#pragma unroll
  for (int h = 0; h < HEADS; ++h) {
    const float val = valid ? (bias_table[idx + h] + mv) * LOG2E : -14427.0f;
    cmb[((long)(w * HEADS + h) * N_TOK + q) * NP + key] = (f16)val;
  }
}

// ---------------------------------------------------------------------------
// Kernel A: MFMA qkv. Block = 128 rows (8 waves x 16), 288 cols.
// wt staged in LDS; epilogues LDS-bounced to coalesced f16x8 stores.
// Q pre-scaled by hd^-0.5 * log2(e)  (attn uses exp2).
// ---------------------------------------------------------------------------
__global__ __launch_bounds__(512) void qkv_mfma_kernel(
    const float* __restrict__ x, const f16* __restrict__ wt,
    const float* __restrict__ bias,
    f16* __restrict__ Q, f16* __restrict__ K, f16* __restrict__ V) {
  __shared__ f16 wtL[QKV_COLS][WT_PITCH];  // 59904 B
  __shared__ f16 sh[8][16][40];            // 10240 B
  const int tid = threadIdx.x;
  const int wave = tid >> 6, lane = tid & 63;
  const int c = lane & 15, g = lane >> 4;
  const long rowTile = (long)blockIdx.x * 128 + wave * 16;
  const long arow = rowTile + c;

  for (int u = tid; u < QKV_COLS * 12; u += 512) {
    const int r = u / 12, ch = u % 12;
    *(f16x8*)&wtL[r][ch * 8] = *(const f16x8*)(wt + r * 96 + ch * 8);
  }

  f16x8 af[3];
#pragma unroll
  for (int ks = 0; ks < 3; ++ks) {
    const float* px = x + arow * 96 + ks * 32 + g * 8;
    const float4 lo = *(const float4*)px;
    const float4 hi = *(const float4*)(px + 4);
    f16x8 v;
    v[0] = (f16)lo.x; v[1] = (f16)lo.y; v[2] = (f16)lo.z; v[3] = (f16)lo.w;
    v[4] = (f16)hi.x; v[5] = (f16)hi.y; v[6] = (f16)hi.z; v[7] = (f16)hi.w;
    af[ks] = v;
  }
  __syncthreads();

  const int rowL = (int)rowTile + (lane >> 2);
  const int bL = rowL / N_TOK, nL = rowL % N_TOK;

  const f32x4 zero = {0.f, 0.f, 0.f, 0.f};
  const float scale = 0.17677669529663687f * 1.4426950408889634f;  // hd^-0.5 * log2e

#pragma unroll
  for (int p = 0; p < 9; ++p) {
    const int which = p / 3;
    const int h = p % 3;
    const float mult = (which == 0) ? scale : 1.0f;
#pragma unroll
    for (int e = 0; e < 2; ++e) {
      const int ct = 2 * p + e;
      f32x4 acc = zero;
#pragma unroll
      for (int ks = 0; ks < 3; ++ks) {
        const f16x8 bf = *(const f16x8*)&wtL[ct * 16 + c][ks * 32 + g * 8];
        acc = __builtin_amdgcn_mfma_f32_16x16x32_f16(af[ks], bf, acc, 0, 0, 0);
      }
      const float bv = bias[ct * 16 + c];
#pragma unroll
      for (int r = 0; r < 4; ++r)
        sh[wave][4 * g + r][(e << 4) + c] = (f16)((acc[r] + bv) * mult);
    }
    __builtin_amdgcn_wave_barrier();
    const f16x8 po = *(const f16x8*)&sh[wave][lane >> 2][(lane & 3) * 8];
    __builtin_amdgcn_wave_barrier();
    f16* dst = (which == 0) ? Q : (which == 1) ? K : V;
    *(f16x8*)(dst + (((long)bL * HEADS + h) * N_TOK + nL) * HD + (lane & 3) * 8) = po;
  }
}

// ---------------------------------------------------------------------------
// Kernel T: V[b][h][n][32] -> VtG[b][h][32][NP] (transposed, zero-padded).
// LDS 64x32 tile transpose; coalesced f16x8 on both sides.
// ---------------------------------------------------------------------------
__global__ __launch_bounds__(256) void vtr_kernel(
    const f16* __restrict__ V, f16* __restrict__ VtG) {
  __shared__ f16 t[64][40];  // pitch 40: gather reads hit 8 distinct banks
  const int blk = blockIdx.x;  // b*HEADS+h
  const f16* src = V + (long)blk * (N_TOK * HD);
  f16* dst = VtG + (long)blk * (HD * NP);
  const int tid = threadIdx.x;

  for (int c0 = 0; c0 < NP; c0 += 64) {
    {
      const int row = tid >> 2;          // 0..63
      const int n = c0 + row;
      const int ch = (tid & 3) * 8;
      f16x8 v = {0, 0, 0, 0, 0, 0, 0, 0};
      if (n < N_TOK) v = *(const f16x8*)(src + n * HD + ch);
      *(f16x8*)&t[row][ch] = v;
    }
    __syncthreads();
    {
      const int d = tid >> 3;            // 0..31
      const int nch = tid & 7;           // 0..7
      const int n0 = c0 + nch * 8;
      if (n0 < NP) {
        f16x8 o;
#pragma unroll
        for (int j = 0; j < 8; ++j) o[j] = t[nch * 8 + j][d];
        *(f16x8*)(dst + d * NP + n0) = o;
      }
    }
    __syncthreads();
  }
}

// ---------------------------------------------------------------------------
// Kernel B: MFMA attention v6 = R7 structure (512 thr, 24 waves/CU) with
// clean coalesced V staging from VtG (the R7 scalar V-transpose staging was
// the serialized prologue). In-lane P k-slot permutation; exp2 path.
// NO min-waves launch-bounds hint (R5/R6 spill lesson).
// ---------------------------------------------------------------------------
__global__ __launch_bounds__(512) void attn_kernel(
    const f16* __restrict__ Qh, const f16* __restrict__ Kh,
    const f16* __restrict__ VtG, const f16* __restrict__ CMB,
    f16* __restrict__ X2h) {
  __shared__ f16 Ks[NP][40];   // 80B stride: 2-way bank aliasing (free)
  __shared__ f16 Vt[HD][356];  // 712B stride

  const int blk = blockIdx.x;
  const int b = blk / HEADS;
  const int h = blk % HEADS;
  const int tid = threadIdx.x;
  const int wave = tid >> 6;
  const int lane = tid & 63;
  const int c = lane & 15;
  const int g = lane >> 4;

  const f16* Kg = Kh + (long)blk * (N_TOK * HD);
  const f16* Vg = VtG + (long)blk * (HD * NP);
  const f16* Qg = Qh + (long)blk * (N_TOK * HD);

  // stage K (zero-padded rows)
  for (int u = tid; u < NP * 4; u += 512) {
    const int key = u >> 2, j = u & 3;
    f16x8 val = {0, 0, 0, 0, 0, 0, 0, 0};
    if (key < N_TOK) val = *(const f16x8*)(Kg + key * HD + j * 8);
    *(f16x8*)&Ks[key][j * 8] = val;
  }
  // stage V (already transposed + zero-padded in global): coalesced f16x8
  for (int u = tid; u < HD * 44; u += 512) {
    const int d = u / 44, ch = (u % 44) * 8;
    *(f16x8*)&Vt[d][ch] = *(const f16x8*)(Vg + d * NP + ch);
  }
  __syncthreads();

  const int w = b & (NW - 1);
  const f32x4 zero = {0.f, 0.f, 0.f, 0.f};

  for (int qt = wave; qt < NP / 16; qt += 8) {
    const int q = qt * 16 + c;
    const int qrow = (q < N_TOK) ? q : (N_TOK - 1);
    const f16x8 qf = *(const f16x8*)(Qg + qrow * HD + g * 8);
    const f16* cmrow = CMB + ((long)(w * HEADS + h) * N_TOK + qrow) * NP;

    f32x4 acc0 = zero, acc1 = zero;
    float lsum = 0.f;

    for (int kt = 0; kt < NKT; ++kt) {
      const f16x8 kf0 = *(const f16x8*)&Ks[32 * kt + c][g * 8];
      const f16x8 kf1 = *(const f16x8*)&Ks[32 * kt + 16 + c][g * 8];
      const f16x4 cm0 = *(const f16x4*)(cmrow + 32 * kt + 4 * g);
      const f16x4 cm1 = *(const f16x4*)(cmrow + 32 * kt + 16 + 4 * g);

      const f32x4 s0 = __builtin_amdgcn_mfma_f32_16x16x32_f16(kf0, qf, zero, 0, 0, 0);
      const f32x4 s1 = __builtin_amdgcn_mfma_f32_16x16x32_f16(kf1, qf, zero, 0, 0, 0);

      float p0[4], p1[4];
#pragma unroll
      for (int r = 0; r < 4; ++r) {
        p0[r] = __builtin_amdgcn_exp2f(s0[r] + (float)cm0[r]);
        p1[r] = __builtin_amdgcn_exp2f(s1[r] + (float)cm1[r]);
        lsum += p0[r] + p1[r];
      }
      // in-lane P fragment: slots 0-3 = keys 4g+r, slots 4-7 = keys 16+4g+r
      const f16x2 a0 = __builtin_bit_cast(f16x2, __builtin_amdgcn_cvt_pkrtz(p0[0], p0[1]));
      const f16x2 a1 = __builtin_bit_cast(f16x2, __builtin_amdgcn_cvt_pkrtz(p0[2], p0[3]));
      const f16x2 a2 = __builtin_bit_cast(f16x2, __builtin_amdgcn_cvt_pkrtz(p1[0], p1[1]));
      const f16x2 a3 = __builtin_bit_cast(f16x2, __builtin_amdgcn_cvt_pkrtz(p1[2], p1[3]));
      const f16x4 plo = __builtin_shufflevector(a0, a1, 0, 1, 2, 3);
      const f16x4 phi = __builtin_shufflevector(a2, a3, 0, 1, 2, 3);
      const f16x8 pf = __builtin_shufflevector(plo, phi, 0, 1, 2, 3, 4, 5, 6, 7);

      // V frags with matching key-slot offsets
      const f16x4 va0 = *(const f16x4*)&Vt[c][32 * kt + 4 * g];
      const f16x4 va1 = *(const f16x4*)&Vt[c][32 * kt + 16 + 4 * g];
      const f16x4 vb0 = *(const f16x4*)&Vt[16 + c][32 * kt + 4 * g];
      const f16x4 vb1 = *(const f16x4*)&Vt[16 + c][32 * kt + 16 + 4 * g];
      const f16x8 vf0 = __builtin_shufflevector(va0, va1, 0, 1, 2, 3, 4, 5, 6, 7);
      const f16x8 vf1 = __builtin_shufflevector(vb0, vb1, 0, 1, 2, 3, 4, 5, 6, 7);

      acc0 = __builtin_amdgcn_mfma_f32_16x16x32_f16(vf0, pf, acc0, 0, 0, 0);
      acc1 = __builtin_amdgcn_mfma_f32_16x16x32_f16(vf1, pf, acc1, 0, 0, 0);
    }

    lsum += __shfl_xor(lsum, 16);
    lsum += __shfl_xor(lsum, 32);
    const float inv = 1.f / lsum;

    if (q < N_TOK) {
      f16* orow = X2h + ((long)b * N_TOK + q) * C_DIM + h * HD;
      f16x4 o0, o1;
#pragma unroll
      for (int r = 0; r < 4; ++r) {
        o0[r] = (f16)(acc0[r] * inv);
        o1[r] = (f16)(acc1[r] * inv);
      }
      *(f16x4*)(orow + 4 * g) = o0;
      *(f16x4*)(orow + 16 + 4 * g) = o1;
    }
  }
}

// ---------------------------------------------------------------------------
// Kernel C: MFMA proj. out = X2h @ wt_proj + b_proj (f32). wt in LDS;
// LDS-bounced coalesced f32x4 stores.
// ---------------------------------------------------------------------------
__global__ __launch_bounds__(256) void proj_mfma_kernel(
    const f16* __restrict__ X2h, const f16* __restrict__ wt,
    const float* __restrict__ bias, float* __restrict__ out) {
  __shared__ f16 wtL[C_DIM][WT_PITCH];  // 19968 B
  __shared__ float shp[4][16][100];     // 25600 B
  const int tid = threadIdx.x;
  const int wave = tid >> 6, lane = tid & 63;
  const int c = lane & 15, g = lane >> 4;
  const long rowTile = (long)blockIdx.x * 64 + wave * 16;
  const long arow = rowTile + c;

  for (int u = tid; u < C_DIM * 12; u += 256) {
    const int r = u / 12, ch = u % 12;
    *(f16x8*)&wtL[r][ch * 8] = *(const f16x8*)(wt + r * 96 + ch * 8);
  }

  f16x8 af[3];
#pragma unroll
  for (int ks = 0; ks < 3; ++ks)
    af[ks] = *(const f16x8*)(X2h + arow * 96 + ks * 32 + g * 8);
  __syncthreads();

  const f32x4 zero = {0.f, 0.f, 0.f, 0.f};
#pragma unroll
  for (int ct = 0; ct < 6; ++ct) {
    f32x4 acc = zero;
#pragma unroll
    for (int ks = 0; ks < 3; ++ks) {
      const f16x8 bf = *(const f16x8*)&wtL[ct * 16 + c][ks * 32 + g * 8];
      acc = __builtin_amdgcn_mfma_f32_16x16x32_f16(af[ks], bf, acc, 0, 0, 0);
    }
    const float bv = bias[ct * 16 + c];
#pragma unroll
    for (int r = 0; r < 4; ++r)
      shp[wave][4 * g + r][ct * 16 + c] = acc[r] + bv;
  }
  __builtin_amdgcn_wave_barrier();
#pragma unroll
  for (int i = 0; i < 6; ++i) {
    const int u = lane + 64 * i;
    const int row = u / 24, ch = u % 24;
    const float4 v = *(const float4*)&shp[wave][row][ch * 4];
    *(float4*)(out + (rowTile + row) * 96 + ch * 4) = v;
  }
}

// ---------------------------------------------------------------------------
extern "C" void kernel_launch(void* const* d_in, const int* in_sizes, int n_in,
                              void* d_out, int out_size, void* d_ws, size_t ws_size,
                              hipStream_t stream) {
  const float* x          = (const float*)d_in[0];
  const float* mask       = (const float*)d_in[1];
  const float* w_qkv      = (const float*)d_in[2];
  const float* b_qkv      = (const float*)d_in[3];
  const float* bias_table = (const float*)d_in[4];
  const float* w_proj     = (const float*)d_in[5];
  const float* b_proj     = (const float*)d_in[6];
  float* out = (float*)d_out;

  f16* Qh = (f16*)d_ws;
  f16* Kh = Qh + QKV_ELEMS;
  f16* Vh = Kh + QKV_ELEMS;
  f16* X2h = Vh + QKV_ELEMS;
  f16* CMB = X2h + X2_ELEMS;
  f16* WTQ = CMB + CMB_ELEMS;
  f16* WTP = WTQ + QKV_COLS * 96;
  f16* VtG = WTP + 96 * 96;

  const int wBlocks = (QKV_COLS * 96 + 96 * 96 + 255) / 256;   // 144
  const int qkvBlocks = (B_SZ * N_TOK) / 128;                   // 686
  const int projBlocks = (B_SZ * N_TOK) / 64;                   // 1372

  wprep_kernel<<<wBlocks, 256, 0, stream>>>(w_qkv, w_proj, WTQ, WTP);
  cmb_kernel<<<dim3(N_TOK, NW), 384, 0, stream>>>(mask, bias_table, CMB);
  qkv_mfma_kernel<<<qkvBlocks, 512, 0, stream>>>(x, WTQ, b_qkv, Qh, Kh, Vh);
  vtr_kernel<<<B_SZ * HEADS, 256, 0, stream>>>(Vh, VtG);
  attn_kernel<<<B_SZ * HEADS, 512, 0, stream>>>(Qh, Kh, VtG, CMB, X2h);
  proj_mfma_kernel<<<projBlocks, 256, 0, stream>>>(X2h, WTP, b_proj, out);
}